// Round 3
// baseline (1904.784 us; speedup 1.0000x reference)
//
#include <hip/hip_runtime.h>
#include <math.h>

// ---------------- problem constants ----------------
#define NHEADS 16
#define HD     32      // head dim
#define HDC    16      // head-dim chunk for K/V LDS staging
#define WA     49      // 7*7 window area
#define NROLL  132     // valid rolled neighbors
#define NKV    181     // WA + NROLL
#define NKVP   184     // padded (mult of 8)
#define WAP    56      // padded query dim (7*8)
#define CDIM   512
#define QKVLD  1536
#define NPIX   25088   // 8*56*56
#define NWIN   512     // 8 * 8 * 8 windows

// ---------------- GEMM: C = A @ W^T + bias ----------------
// A (M,K) row-major, W (N,K) row-major, C (M,N). M%64==0, N%64==0, K%32==0.
#define BM 64
#define BN 64
#define BK 32

__global__ __launch_bounds__(256) void gemm_bias(
    const float* __restrict__ A, const float* __restrict__ W,
    const float* __restrict__ bias, float* __restrict__ C,
    int M, int N, int K)
{
    __shared__ float As[BK][BM];
    __shared__ float Bs[BK][BN];
    const int tid = threadIdx.x;
    const int m0 = blockIdx.y * BM;
    const int n0 = blockIdx.x * BN;
    const int tm = (tid >> 4) << 2;   // 0..60
    const int tn = (tid & 15) << 2;   // 0..60
    const int lr = tid >> 3;          // 0..31
    const int lc = (tid & 7) << 2;    // 0..28

    float acc[4][4] = {};

    for (int k0 = 0; k0 < K; k0 += BK) {
        const float4 a0 = *(const float4*)(A + (m0 + lr) * K + k0 + lc);
        const float4 a1 = *(const float4*)(A + (m0 + lr + 32) * K + k0 + lc);
        const float4 b0 = *(const float4*)(W + (n0 + lr) * K + k0 + lc);
        const float4 b1 = *(const float4*)(W + (n0 + lr + 32) * K + k0 + lc);
        __syncthreads();   // prev iteration's LDS reads done before overwrite
        As[lc + 0][lr] = a0.x; As[lc + 1][lr] = a0.y; As[lc + 2][lr] = a0.z; As[lc + 3][lr] = a0.w;
        As[lc + 0][lr + 32] = a1.x; As[lc + 1][lr + 32] = a1.y; As[lc + 2][lr + 32] = a1.z; As[lc + 3][lr + 32] = a1.w;
        Bs[lc + 0][lr] = b0.x; Bs[lc + 1][lr] = b0.y; Bs[lc + 2][lr] = b0.z; Bs[lc + 3][lr] = b0.w;
        Bs[lc + 0][lr + 32] = b1.x; Bs[lc + 1][lr + 32] = b1.y; Bs[lc + 2][lr + 32] = b1.z; Bs[lc + 3][lr + 32] = b1.w;
        __syncthreads();
        #pragma unroll
        for (int kk = 0; kk < BK; ++kk) {
            const float4 a4 = *(const float4*)(&As[kk][tm]);
            const float4 b4 = *(const float4*)(&Bs[kk][tn]);
            const float ar[4] = {a4.x, a4.y, a4.z, a4.w};
            const float br[4] = {b4.x, b4.y, b4.z, b4.w};
            #pragma unroll
            for (int i = 0; i < 4; ++i)
                #pragma unroll
                for (int j = 0; j < 4; ++j)
                    acc[i][j] = fmaf(ar[i], br[j], acc[i][j]);
        }
    }

    const float4 bv = *(const float4*)(bias + n0 + tn);
    const float br[4] = {bv.x, bv.y, bv.z, bv.w};
    #pragma unroll
    for (int i = 0; i < 4; ++i) {
        float4 o;
        o.x = acc[i][0] + br[0];
        o.y = acc[i][1] + br[1];
        o.z = acc[i][2] + br[2];
        o.w = acc[i][3] + br[3];
        *(float4*)(C + (m0 + tm + i) * N + n0 + tn) = o;
    }
}

// ---------------- window attention ----------------
// roll order: s=0:(-3,-3) tl, s=1:(-3,+3) tr, s=2:(+3,-3) bl, s=3:(+3,+3) br
__device__ __forceinline__ bool roll_valid(int j) {
    const int s = j / 49, rc = j % 49, r = rc / 7, c = rc % 7;
    if (s == 0) return (r >= 4) || (c >= 4);
    if (s == 1) return (r >= 4) || (c <= 2);
    if (s == 2) return (r <= 2) || (c >= 4);
    return (r <= 2) || (c <= 2);
}

// source pixel (h,w) for kv index (0..180) in window at (h0,w0c)
__device__ __forceinline__ void kv_src(int kv, int h0, int w0c, const int* rtab,
                                       int& h, int& wc) {
    if (kv < WA) {
        h = h0 + kv / 7; wc = w0c + kv % 7;
    } else {
        const int j = rtab[kv - WA];
        const int s = j / 49, rc = j % 49, r = rc / 7, c = rc % 7;
        const int sh = (s < 2) ? -3 : 3;
        const int sw = (s & 1) ? 3 : -3;
        h  = (h0 + r - sh + 56) % 56;      // rolled[h] = orig[h - sh]
        wc = (w0c + c - sw + 56) % 56;
    }
}

__global__ __launch_bounds__(256) void attn_win(
    const float* __restrict__ qkv,   // (25088, 1536): q|k|v
    const float* __restrict__ rpbt,  // (169, 16)
    const float* __restrict__ rpbn,  // (16, 49, 132)
    float* __restrict__ aout)        // (25088, 512)
{
    // static LDS: 528 + 7168 + 11776 + 35476 = 54948 B  (<= 64 KiB, no attribute games)
    __shared__ int   rtab[NROLL];
    __shared__ float qst[HD][WAP];     // q transposed (d, qi), scaled
    __shared__ float kvb[HDC][NKVP];   // k/v chunk, transposed (d_local, kv)
    __shared__ float pr[WA][NKV];      // logits -> probs

    const int tid  = threadIdx.x;
    const int w    = blockIdx.x >> 4;
    const int head = blockIdx.x & 15;
    const int b  = w >> 6;
    const int hw = (w >> 3) & 7;
    const int ww = w & 7;
    const int h0 = hw * 7, w0c = ww * 7;
    const int pixbase = b * 3136;
    const float scale = 0.17677669529663687f;  // 32^-0.5

    // ---- P0: rolled-index table (np.nonzero order) + q load + pads ----
    if (tid < 196 && roll_valid(tid)) {
        int pos = 0;
        for (int i = 0; i < tid; ++i) pos += roll_valid(i) ? 1 : 0;
        rtab[pos] = tid;
    }
    for (int idx = tid; idx < WA * HD; idx += 256) {
        const int qi = idx >> 5, d = idx & 31;
        const int h = h0 + qi / 7, wc = w0c + qi % 7;
        qst[d][qi] = qkv[(pixbase + h * 56 + wc) * QKVLD + head * HD + d] * scale;
    }
    if (tid < HD * (WAP - WA)) qst[tid / (WAP - WA)][WA + tid % (WAP - WA)] = 0.f;  // qi 49..55
    __syncthreads();

    // ---- P1: logits over two d-chunks of K ----
    const int qt = tid / 23, kt = tid % 23;        // valid when tid<161
    const int qi0 = qt * 8, k0 = kt * 8;
    float acc[8][8] = {};
    for (int half = 0; half < 2; ++half) {
        for (int idx = tid; idx < NKV * HDC; idx += 256) {
            const int kv = idx >> 4, dd = idx & 15;
            int h, wc; kv_src(kv, h0, w0c, rtab, h, wc);
            kvb[dd][kv] = qkv[(pixbase + h * 56 + wc) * QKVLD + CDIM + head * HD + half * HDC + dd];
        }
        if (tid < HDC * (NKVP - NKV)) kvb[tid / 3][NKV + tid % 3] = 0.f;  // kv 181..183
        __syncthreads();
        if (tid < 161) {
            #pragma unroll
            for (int dd = 0; dd < HDC; ++dd) {
                const float4 qa = *(const float4*)(&qst[half * HDC + dd][qi0]);
                const float4 qb = *(const float4*)(&qst[half * HDC + dd][qi0 + 4]);
                const float4 ka = *(const float4*)(&kvb[dd][k0]);
                const float4 kb = *(const float4*)(&kvb[dd][k0 + 4]);
                const float qr[8] = {qa.x, qa.y, qa.z, qa.w, qb.x, qb.y, qb.z, qb.w};
                const float kr[8] = {ka.x, ka.y, ka.z, ka.w, kb.x, kb.y, kb.z, kb.w};
                #pragma unroll
                for (int i = 0; i < 8; ++i)
                    #pragma unroll
                    for (int j = 0; j < 8; ++j)
                        acc[i][j] = fmaf(qr[i], kr[j], acc[i][j]);
            }
        }
        __syncthreads();   // acc done before kvb overwrite (next half / v-load)
    }
    // bias + store logits
    if (tid < 161) {
        for (int i = 0; i < 8; ++i) {
            const int qi = qi0 + i;
            if (qi >= WA) break;
            const int r1 = qi / 7, c1 = qi % 7;
            for (int j = 0; j < 8; ++j) {
                const int k = k0 + j;
                if (k >= NKV) break;
                float bias;
                if (k < WA) {
                    const int r2 = k / 7, c2 = k % 7;
                    bias = rpbt[((r1 - r2 + 6) * 13 + (c1 - c2 + 6)) * NHEADS + head];
                } else {
                    bias = rpbn[(head * WA + qi) * NROLL + (k - WA)];
                }
                pr[qi][k] = acc[i][j] + bias;
            }
        }
    }
    __syncthreads();

    // ---- P2: v chunk 0 load + wave-parallel softmax ----
    for (int idx = tid; idx < NKV * HDC; idx += 256) {
        const int kv = idx >> 4, dd = idx & 15;
        int h, wc; kv_src(kv, h0, w0c, rtab, h, wc);
        kvb[dd][kv] = qkv[(pixbase + h * 56 + wc) * QKVLD + 2 * CDIM + head * HD + dd];
    }
    {
        const int lane = tid & 63, wv = tid >> 6;
        for (int qi = wv; qi < WA; qi += 4) {
            float* row = pr[qi];
            const float v0 = row[lane];
            const float v1 = row[lane + 64];
            const bool has2 = (lane + 128 < NKV);
            const float v2 = has2 ? row[lane + 128] : -1e30f;
            float m = fmaxf(fmaxf(v0, v1), v2);
            #pragma unroll
            for (int off = 32; off >= 1; off >>= 1) m = fmaxf(m, __shfl_xor(m, off));
            const float e0 = __expf(v0 - m);
            const float e1 = __expf(v1 - m);
            const float e2 = has2 ? __expf(v2 - m) : 0.f;
            float s = e0 + e1 + e2;
            #pragma unroll
            for (int off = 32; off >= 1; off >>= 1) s += __shfl_xor(s, off);
            const float inv = 1.f / s;
            row[lane] = e0 * inv;
            row[lane + 64] = e1 * inv;
            if (has2) row[lane + 128] = e2 * inv;
        }
    }
    __syncthreads();

    // ---- P3: PV in two d-chunks (tid<100: 25 q-tiles of 2 rows x 4 d-tiles of 4) ----
    for (int half = 0; half < 2; ++half) {
        if (half == 1) {
            // load v chunk 1 (kvb last read by PV chunk 0; barrier below separates)
            for (int idx = tid; idx < NKV * HDC; idx += 256) {
                const int kv = idx >> 4, dd = idx & 15;
                int h, wc; kv_src(kv, h0, w0c, rtab, h, wc);
                kvb[dd][kv] = qkv[(pixbase + h * 56 + wc) * QKVLD + 2 * CDIM + head * HD + HDC + dd];
            }
            __syncthreads();
        }
        if (tid < 100) {
            const int qt = tid >> 2, dt = tid & 3;
            const int qi0p = qt * 2, d0 = dt * 4;
            const float* p0 = pr[(qi0p < WA) ? qi0p : (WA - 1)];
            const float* p1 = pr[(qi0p + 1 < WA) ? (qi0p + 1) : (WA - 1)];
            float a2[2][4] = {};
            for (int k = 0; k < NKV; ++k) {
                const float pv[2] = {p0[k], p1[k]};
                const float vv[4] = {kvb[d0 + 0][k], kvb[d0 + 1][k], kvb[d0 + 2][k], kvb[d0 + 3][k]};
                #pragma unroll
                for (int i = 0; i < 2; ++i)
                    #pragma unroll
                    for (int j = 0; j < 4; ++j)
                        a2[i][j] = fmaf(pv[i], vv[j], a2[i][j]);
            }
            #pragma unroll
            for (int i = 0; i < 2; ++i) {
                const int qi = qi0p + i;
                if (qi >= WA) continue;
                float4 o;
                o.x = a2[i][0]; o.y = a2[i][1]; o.z = a2[i][2]; o.w = a2[i][3];
                *(float4*)(aout + (w * WA + qi) * CDIM + head * HD + half * HDC + d0) = o;
            }
        }
        if (half == 0) __syncthreads();  // PV0 reads done before v chunk 1 overwrite
    }
}

// ---------------- launch ----------------
extern "C" void kernel_launch(void* const* d_in, const int* in_sizes, int n_in,
                              void* d_out, int out_size, void* d_ws, size_t ws_size,
                              hipStream_t stream)
{
    const float* x      = (const float*)d_in[0];
    const float* qkv_w  = (const float*)d_in[1];
    const float* qkv_b  = (const float*)d_in[2];
    const float* proj_w = (const float*)d_in[3];
    const float* proj_b = (const float*)d_in[4];
    const float* rpbt   = (const float*)d_in[5];
    const float* rpbn   = (const float*)d_in[6];

    float* qkv  = (float*)d_ws;                        // (25088, 1536)
    float* aout = qkv + (size_t)NPIX * QKVLD;          // (25088, 512)
    const size_t need = ((size_t)NPIX * QKVLD + (size_t)NPIX * CDIM) * sizeof(float);
    if (ws_size < need) return;  // workspace too small: fail visibly, don't corrupt

    // QKV projection
    gemm_bias<<<dim3(QKVLD / BN, NPIX / BM), 256, 0, stream>>>(
        x, qkv_w, qkv_b, qkv, NPIX, QKVLD, CDIM);

    // windowed attention (one block per window x head; static LDS only)
    attn_win<<<NWIN * NHEADS, 256, 0, stream>>>(qkv, rpbt, rpbn, aout);

    // output projection
    gemm_bias<<<dim3(CDIM / BN, NPIX / BM), 256, 0, stream>>>(
        aout, proj_w, proj_b, (float*)d_out, NPIX, CDIM, CDIM);
}

// Round 4
// 391.590 us; speedup vs baseline: 4.8642x; 4.8642x over previous
//
#include <hip/hip_runtime.h>
#include <math.h>

typedef unsigned short u16;
typedef unsigned int   u32;
typedef __attribute__((ext_vector_type(8))) short short8;   // 8 bf16 (4 VGPR)
typedef __attribute__((ext_vector_type(4))) float f32x4;

// ---------------- problem constants ----------------
#define NHEADS 16
#define HD     32
#define WA     49
#define NROLL  132
#define NKV    181     // WA + NROLL
#define NKVT   192     // 12 tiles of 16
#define CDIM   512
#define QKVLD  1536
#define NPIX   25088   // 8*56*56
#define NWIN   512
// LDS pitches (bf16 elems; rows 16B-aligned, bank-spread)
#define QP 40
#define KP 40
#define VP 200
#define PP 216

__device__ __forceinline__ u16 f32_to_bf16(float f) {
    union { float f; u32 u; } x; x.f = f;
    u32 r = x.u + 0x7FFFu + ((x.u >> 16) & 1u);   // RNE
    return (u16)(r >> 16);
}

// ---------------- fp32 -> bf16 conversion ----------------
__global__ __launch_bounds__(256) void cvt_bf16(const float* __restrict__ in,
                                                u16* __restrict__ out, int n) {
    int i = (blockIdx.x * 256 + threadIdx.x) * 4;
    if (i >= n) return;
    float4 v = *(const float4*)(in + i);
    *(ushort4*)(out + i) = make_ushort4(f32_to_bf16(v.x), f32_to_bf16(v.y),
                                        f32_to_bf16(v.z), f32_to_bf16(v.w));
}

// ---------------- bf16 MFMA GEMM: C = A @ W^T + bias ----------------
// A (M,K) bf16 row-major, W (N,K) bf16 row-major. M%128==0, N%128==0, K%32==0.
template<bool STORE_BF16>
__global__ __launch_bounds__(256) void gemm_mfma(
    const u16* __restrict__ A, const u16* __restrict__ W,
    const float* __restrict__ bias, void* __restrict__ Cv,
    int M, int N, int K)
{
    __shared__ __align__(16) u16 As[128 * 32];
    __shared__ __align__(16) u16 Bs[128 * 32];
    const int tid = threadIdx.x;
    const int lane = tid & 63, wv = tid >> 6;
    const int m0 = blockIdx.y * 128, n0 = blockIdx.x * 128;
    const int wr = (wv >> 1) * 64, wc = (wv & 1) * 64;
    const int lr = lane & 15;           // frag row
    const int lk = (lane >> 4) * 8;     // frag k-offset
    const int srow = lane >> 2;         // staging row within 16-block
    const int scol = (lane & 3) * 8;    // staging col (elems)

    f32x4 acc[4][4] = {};

    for (int k0 = 0; k0 < K; k0 += 32) {
        __syncthreads();   // prior frag reads done before LDS overwrite
        #pragma unroll
        for (int blk = 0; blk < 2; ++blk) {
            const int r = wv * 32 + blk * 16;
            __builtin_amdgcn_global_load_lds(
                (const __attribute__((address_space(1))) void*)
                    (A + (size_t)(m0 + r + srow) * K + k0 + scol),
                (__attribute__((address_space(3))) void*)(As + r * 32), 16, 0, 0);
            __builtin_amdgcn_global_load_lds(
                (const __attribute__((address_space(1))) void*)
                    (W + (size_t)(n0 + r + srow) * K + k0 + scol),
                (__attribute__((address_space(3))) void*)(Bs + r * 32), 16, 0, 0);
        }
        __syncthreads();   // staging visible
        #pragma unroll
        for (int mi = 0; mi < 4; ++mi) {
            const short8 af = *(const short8*)(As + (wr + mi * 16 + lr) * 32 + lk);
            #pragma unroll
            for (int ni = 0; ni < 4; ++ni) {
                const short8 bf = *(const short8*)(Bs + (wc + ni * 16 + lr) * 32 + lk);
                acc[mi][ni] = __builtin_amdgcn_mfma_f32_16x16x32_bf16(af, bf, acc[mi][ni], 0, 0, 0);
            }
        }
    }

    const int col0 = n0 + wc + lr;
    #pragma unroll
    for (int ni = 0; ni < 4; ++ni) {
        const float bcol = bias[col0 + ni * 16];
        #pragma unroll
        for (int mi = 0; mi < 4; ++mi)
            #pragma unroll
            for (int r = 0; r < 4; ++r) {
                const int row = m0 + wr + mi * 16 + (lane >> 4) * 4 + r;
                const float v = acc[mi][ni][r] + bcol;
                if (STORE_BF16)
                    ((u16*)Cv)[(size_t)row * N + col0 + ni * 16] = f32_to_bf16(v);
                else
                    ((float*)Cv)[(size_t)row * N + col0 + ni * 16] = v;
            }
    }
}

// ---------------- rolled-neighbor offset table (np.nonzero order) ----------------
struct OffT { int dr[NROLL]; int dc[NROLL]; };
constexpr bool rvalid(int s, int r, int c) {
    return (s == 0) ? (r >= 4 || c >= 4) :
           (s == 1) ? (r >= 4 || c <= 2) :
           (s == 2) ? (r <= 2 || c >= 4) :
                      (r <= 2 || c <= 2);
}
constexpr OffT make_offt() {
    OffT t{};
    int p = 0;
    for (int s = 0; s < 4; ++s)
        for (int r = 0; r < 7; ++r)
            for (int c = 0; c < 7; ++c)
                if (rvalid(s, r, c)) {
                    const int sh = (s < 2) ? -3 : 3;
                    const int sw = (s & 1) ? 3 : -3;
                    t.dr[p] = r - sh;   // rolled[h] = orig[h - sh]
                    t.dc[p] = c - sw;
                    ++p;
                }
    return t;
}
__device__ constexpr OffT OFT = make_offt();

// ---------------- MFMA window attention ----------------
__global__ __launch_bounds__(256) void attn_win(
    const u16* __restrict__ qkvb,    // (25088, 1536) bf16: q|k|v
    const float* __restrict__ rpbt,  // (169, 16)
    const float* __restrict__ rpbn,  // (16, 49, 132)
    u16* __restrict__ aob)           // (25088, 512) bf16
{
    __shared__ __align__(16) u16 Qs[64 * QP];    // 5120 B
    __shared__ __align__(16) u16 Ks[NKVT * KP];  // 15360 B
    __shared__ __align__(16) u16 Vt[32 * VP];    // 12800 B  (V transposed: [d][kv])
    __shared__ __align__(16) u16 Ps[64 * PP];    // 27648 B  (P bf16: [qi][kv])
    __shared__ int pixt[NKV];                    // 724 B    total 61,652 B

    const int tid  = threadIdx.x;
    const int lane = tid & 63, wv = tid >> 6;
    const int w    = blockIdx.x >> 4;
    const int head = blockIdx.x & 15;
    const int b    = w >> 6;
    const int h0   = ((w >> 3) & 7) * 7;
    const int w0c  = (w & 7) * 7;
    const int pixbase = b * 3136;

    // ---- pixel-row table: row base offset (bf16 elems) per kv ----
    if (tid < NKV) {
        int h, wc;
        if (tid < WA) { h = h0 + tid / 7; wc = w0c + tid % 7; }
        else {
            const int i = tid - WA;
            h = h0 + OFT.dr[i];  h += (h < 0) ? 56 : 0;  h -= (h >= 56) ? 56 : 0;
            wc = w0c + OFT.dc[i]; wc += (wc < 0) ? 56 : 0; wc -= (wc >= 56) ? 56 : 0;
        }
        pixt[tid] = (pixbase + h * 56 + wc) * QKVLD + head * HD;
    }
    __syncthreads();

    // ---- staging: Q, K (row-major, pitch 40), V transposed (pitch 200) ----
    for (int idx = tid; idx < WA * 16; idx += 256) {          // Q: 49 rows x 16 pairs
        const int qi = idx >> 4, dp = idx & 15;
        *(u32*)(Qs + qi * QP + dp * 2) = *(const u32*)(qkvb + pixt[qi] + dp * 2);
    }
    for (int idx = tid; idx < NKV * 16; idx += 256) {         // K
        const int kv = idx >> 4, dp = idx & 15;
        *(u32*)(Ks + kv * KP + dp * 2) = *(const u32*)(qkvb + pixt[kv] + CDIM + dp * 2);
    }
    for (int idx = tid; idx < NKV * 16; idx += 256) {         // V -> Vt
        const int kv = idx >> 4, dp = idx & 15;
        const u32 v = *(const u32*)(qkvb + pixt[kv] + 2 * CDIM + dp * 2);
        Vt[(2 * dp) * VP + kv]     = (u16)(v & 0xffffu);
        Vt[(2 * dp + 1) * VP + kv] = (u16)(v >> 16);
    }
    for (int idx = tid; idx < 32 * (NKVT - NKV); idx += 256) { // Vt zero-pad kv 181..191
        const int d = idx / (NKVT - NKV), kv = NKV + idx % (NKVT - NKV);
        Vt[d * VP + kv] = 0;
    }
    __syncthreads();

    // ---- QK^T: wave wv owns q-rows [16wv, 16wv+16); 12 n-tiles ----
    const int lr = lane & 15;
    const int lk = (lane >> 4) * 8;
    const int qrow0 = 16 * wv + (lane >> 4) * 4;   // + r
    const short8 aq = *(const short8*)(Qs + (16 * wv + lr) * QP + lk);
    f32x4 s[12];
    #pragma unroll
    for (int n = 0; n < 12; ++n) {
        const short8 bk = *(const short8*)(Ks + (n * 16 + lr) * KP + lk);
        s[n] = __builtin_amdgcn_mfma_f32_16x16x32_bf16(aq, bk, (f32x4){0.f, 0.f, 0.f, 0.f}, 0, 0, 0);
    }

    // ---- scale + bias + mask (per C element) ----
    const float scale = 0.17677669529663687f;  // 32^-0.5
    #pragma unroll
    for (int n = 0; n < 12; ++n) {
        const int kv = n * 16 + lr;
        #pragma unroll
        for (int r = 0; r < 4; ++r) {
            const int qi = qrow0 + r;
            float v;
            if (qi < WA && kv < NKV) {
                v = s[n][r] * scale;
                if (kv < WA) {
                    const int r1 = qi / 7, c1 = qi % 7, r2 = kv / 7, c2 = kv % 7;
                    v += rpbt[((r1 - r2 + 6) * 13 + (c1 - c2 + 6)) * NHEADS + head];
                } else {
                    v += rpbn[((size_t)head * WA + qi) * NROLL + (kv - WA)];
                }
            } else {
                v = (qi < WA) ? -1e30f : 0.f;   // mask pad cols; pad rows benign
            }
            s[n][r] = v;
        }
    }

    // ---- softmax in registers (row = 16-lane group x 12 regs) ----
    float mx[4], sm[4];
    #pragma unroll
    for (int r = 0; r < 4; ++r) {
        float m = s[0][r];
        #pragma unroll
        for (int n = 1; n < 12; ++n) m = fmaxf(m, s[n][r]);
        #pragma unroll
        for (int off = 1; off <= 8; off <<= 1) m = fmaxf(m, __shfl_xor(m, off));
        mx[r] = m;
    }
    #pragma unroll
    for (int r = 0; r < 4; ++r) {
        float t = 0.f;
        #pragma unroll
        for (int n = 0; n < 12; ++n) { const float e = __expf(s[n][r] - mx[r]); s[n][r] = e; t += e; }
        #pragma unroll
        for (int off = 1; off <= 8; off <<= 1) t += __shfl_xor(t, off);
        sm[r] = 1.f / t;
    }
    #pragma unroll
    for (int n = 0; n < 12; ++n)
        #pragma unroll
        for (int r = 0; r < 4; ++r)
            Ps[(qrow0 + r) * PP + n * 16 + lr] = f32_to_bf16(s[n][r] * sm[r]);
    // (wave-private rows: written and read by the same wave only — no barrier needed)

    // ---- PV: O(16x32) per wave = 2 n-tiles x 6 k-chunks ----
    short8 pa[6];
    #pragma unroll
    for (int kk = 0; kk < 6; ++kk)
        pa[kk] = *(const short8*)(Ps + (16 * wv + lr) * PP + kk * 32 + lk);
    #pragma unroll
    for (int n0 = 0; n0 < 2; ++n0) {
        f32x4 o = {0.f, 0.f, 0.f, 0.f};
        #pragma unroll
        for (int kk = 0; kk < 6; ++kk) {
            const short8 vb = *(const short8*)(Vt + (n0 * 16 + lr) * VP + kk * 32 + lk);
            o = __builtin_amdgcn_mfma_f32_16x16x32_bf16(pa[kk], vb, o, 0, 0, 0);
        }
        #pragma unroll
        for (int r = 0; r < 4; ++r) {
            const int qi = qrow0 + r;
            if (qi < WA)
                aob[(size_t)(w * WA + qi) * CDIM + head * HD + n0 * 16 + lr] = f32_to_bf16(o[r]);
        }
    }
}

// ---------------- launch ----------------
extern "C" void kernel_launch(void* const* d_in, const int* in_sizes, int n_in,
                              void* d_out, int out_size, void* d_ws, size_t ws_size,
                              hipStream_t stream)
{
    const float* x      = (const float*)d_in[0];
    const float* qkv_w  = (const float*)d_in[1];
    const float* qkv_b  = (const float*)d_in[2];
    const float* proj_w = (const float*)d_in[3];
    const float* proj_b = (const float*)d_in[4];
    const float* rpbt   = (const float*)d_in[5];
    const float* rpbn   = (const float*)d_in[6];

    // workspace carve-out (bf16 buffers)
    u16* xb   = (u16*)d_ws;                         // (25088, 512)
    u16* qkvb = xb + (size_t)NPIX * CDIM;           // (25088, 1536)
    u16* aob  = qkvb + (size_t)NPIX * QKVLD;        // (25088, 512)
    u16* qwb  = aob + (size_t)NPIX * CDIM;          // (1536, 512)
    u16* pwb  = qwb + (size_t)QKVLD * CDIM;         // (512, 512)
    const size_t need = ((size_t)NPIX * CDIM + (size_t)NPIX * QKVLD + (size_t)NPIX * CDIM
                         + (size_t)QKVLD * CDIM + (size_t)CDIM * CDIM) * sizeof(u16);
    if (ws_size < need) return;

    // fp32 -> bf16
    {
        const int nx = NPIX * CDIM;
        cvt_bf16<<<(nx / 4 + 255) / 256, 256, 0, stream>>>(x, xb, nx);
        const int nq = QKVLD * CDIM;
        cvt_bf16<<<(nq / 4 + 255) / 256, 256, 0, stream>>>(qkv_w, qwb, nq);
        const int np = CDIM * CDIM;
        cvt_bf16<<<(np / 4 + 255) / 256, 256, 0, stream>>>(proj_w, pwb, np);
    }

    // QKV projection (bf16 out)
    gemm_mfma<true><<<dim3(QKVLD / 128, NPIX / 128), 256, 0, stream>>>(
        xb, qwb, qkv_b, qkvb, NPIX, QKVLD, CDIM);

    // windowed attention (bf16 out)
    attn_win<<<NWIN * NHEADS, 256, 0, stream>>>(qkvb, rpbt, rpbn, aob);

    // output projection (fp32 out)
    gemm_mfma<false><<<dim3(CDIM / 128, NPIX / 128), 256, 0, stream>>>(
        aob, pwb, proj_b, d_out, NPIX, CDIM, CDIM);
}

// Round 7
// 229.067 us; speedup vs baseline: 8.3154x; 1.7095x over previous
//
#include <hip/hip_runtime.h>
#include <math.h>

typedef unsigned short u16;
typedef unsigned int   u32;
typedef unsigned long long u64;
typedef __attribute__((ext_vector_type(8))) short short8;   // 8 bf16 (4 VGPR)
typedef __attribute__((ext_vector_type(4))) float f32x4;

// ---------------- problem constants ----------------
#define NHEADS 16
#define HD     32
#define WA     49
#define NROLL  132
#define NKV    181     // WA + NROLL
#define NKVT   192     // 12 tiles of 16
#define CDIM   512
#define QKVLD  1536
#define NPIX   25088   // 8*56*56
#define NWIN   512
// LDS pitches (bf16 elems)
#define QP 40
#define KP 40
#define VP 200
#define PP 104        // P overlay pitch (96 kv + 8 pad)

__device__ __forceinline__ u16 f32_to_bf16(float f) {
    union { float f; u32 u; } x; x.f = f;
    u32 r = x.u + 0x7FFFu + ((x.u >> 16) & 1u);   // RNE
    return (u16)(r >> 16);
}

// ---------------- fp32 -> bf16 conversion ----------------
__global__ __launch_bounds__(256) void cvt_bf16(const float* __restrict__ in,
                                                u16* __restrict__ out, int n) {
    int i = (blockIdx.x * 256 + threadIdx.x) * 4;
    if (i >= n) return;
    float4 v = *(const float4*)(in + i);
    *(ushort4*)(out + i) = make_ushort4(f32_to_bf16(v.x), f32_to_bf16(v.y),
                                        f32_to_bf16(v.z), f32_to_bf16(v.w));
}

// ---------------- bias table: bt[16][192][64]  (head, kv, qi), mask baked in ----------------
__global__ __launch_bounds__(256) void build_bias(
    const float* __restrict__ rpbt,   // (169,16)
    const float* __restrict__ rpbn,   // (16,49,132)
    float* __restrict__ bt)
{
    const int idx = blockIdx.x * 256 + threadIdx.x;   // 16*192*64 = 196608
    const int h   = idx / (NKVT * 64);                // stride 12288 (NOT a power of 2)
    const int rem = idx - h * (NKVT * 64);
    const int kv  = rem >> 6;
    const int qi  = rem & 63;
    float v = -1e30f;
    if (qi < WA && kv < NKV) {
        if (kv < WA) {
            const int r1 = qi / 7, c1 = qi % 7, r2 = kv / 7, c2 = kv % 7;
            v = rpbt[((r1 - r2 + 6) * 13 + (c1 - c2 + 6)) * NHEADS + h];
        } else {
            v = rpbn[(h * WA + qi) * NROLL + (kv - WA)];
        }
    }
    bt[idx] = v;
}

// ---------------- bf16 MFMA GEMM: C = A @ W^T + bias ----------------
template<bool STORE_BF16>
__global__ __launch_bounds__(256) void gemm_mfma(
    const u16* __restrict__ A, const u16* __restrict__ W,
    const float* __restrict__ bias, void* __restrict__ Cv,
    int M, int N, int K)
{
    __shared__ __align__(16) u16 As[128 * 32];
    __shared__ __align__(16) u16 Bs[128 * 32];
    const int tid = threadIdx.x;
    const int lane = tid & 63, wv = tid >> 6;
    const int m0 = blockIdx.y * 128, n0 = blockIdx.x * 128;
    const int wr = (wv >> 1) * 64, wc = (wv & 1) * 64;
    const int lr = lane & 15;
    const int lk = (lane >> 4) * 8;
    const int srow = lane >> 2;
    const int scol = (lane & 3) * 8;

    f32x4 acc[4][4] = {};

    for (int k0 = 0; k0 < K; k0 += 32) {
        __syncthreads();
        #pragma unroll
        for (int blk = 0; blk < 2; ++blk) {
            const int r = wv * 32 + blk * 16;
            __builtin_amdgcn_global_load_lds(
                (const __attribute__((address_space(1))) void*)
                    (A + (size_t)(m0 + r + srow) * K + k0 + scol),
                (__attribute__((address_space(3))) void*)(As + r * 32), 16, 0, 0);
            __builtin_amdgcn_global_load_lds(
                (const __attribute__((address_space(1))) void*)
                    (W + (size_t)(n0 + r + srow) * K + k0 + scol),
                (__attribute__((address_space(3))) void*)(Bs + r * 32), 16, 0, 0);
        }
        __syncthreads();
        #pragma unroll
        for (int mi = 0; mi < 4; ++mi) {
            const short8 af = *(const short8*)(As + (wr + mi * 16 + lr) * 32 + lk);
            #pragma unroll
            for (int ni = 0; ni < 4; ++ni) {
                const short8 bf = *(const short8*)(Bs + (wc + ni * 16 + lr) * 32 + lk);
                acc[mi][ni] = __builtin_amdgcn_mfma_f32_16x16x32_bf16(af, bf, acc[mi][ni], 0, 0, 0);
            }
        }
    }

    const int col0 = n0 + wc + lr;
    #pragma unroll
    for (int ni = 0; ni < 4; ++ni) {
        const float bcol = bias[col0 + ni * 16];
        #pragma unroll
        for (int mi = 0; mi < 4; ++mi)
            #pragma unroll
            for (int r = 0; r < 4; ++r) {
                const int row = m0 + wr + mi * 16 + (lane >> 4) * 4 + r;
                const float v = acc[mi][ni][r] + bcol;
                if (STORE_BF16)
                    ((u16*)Cv)[(size_t)row * N + col0 + ni * 16] = f32_to_bf16(v);
                else
                    ((float*)Cv)[(size_t)row * N + col0 + ni * 16] = v;
            }
    }
}

// ---------------- rolled-neighbor offset table (np.nonzero order) ----------------
struct OffT { int dr[NROLL]; int dc[NROLL]; };
constexpr bool rvalid(int s, int r, int c) {
    return (s == 0) ? (r >= 4 || c >= 4) :
           (s == 1) ? (r >= 4 || c <= 2) :
           (s == 2) ? (r <= 2 || c >= 4) :
                      (r <= 2 || c <= 2);
}
constexpr OffT make_offt() {
    OffT t{};
    int p = 0;
    for (int s = 0; s < 4; ++s)
        for (int r = 0; r < 7; ++r)
            for (int c = 0; c < 7; ++c)
                if (rvalid(s, r, c)) {
                    const int sh = (s < 2) ? -3 : 3;
                    const int sw = (s & 1) ? 3 : -3;
                    t.dr[p] = r - sh;   // rolled[h] = orig[h - sh]
                    t.dc[p] = c - sw;
                    ++p;
                }
    return t;
}
__device__ constexpr OffT OFT = make_offt();

// ---------------- MFMA window attention ----------------
__global__ __launch_bounds__(256) void attn_win(
    const u16* __restrict__ qkvb,    // (25088, 1536) bf16: q|k|v
    const float* __restrict__ bt,    // (16, 192, 64) bias table, mask baked
    u16* __restrict__ aob)           // (25088, 512) bf16
{
    // Qs 5120 + Ks 15360 (P overlay 13312) + Vt 12800 + pixt 724 = 34,004 B -> 4 blocks/CU
    __shared__ __align__(16) u16 smem[64 * QP + NKVT * KP + 32 * VP];
    __shared__ int pixt[NKV];
    u16* const Qs = smem;
    u16* const Ks = smem + 64 * QP;
    u16* const Vt = Ks + NKVT * KP;
    u16* const Ps = Ks;                 // overlay (after barrier)

    const int tid  = threadIdx.x;
    const int lane = tid & 63, wv = tid >> 6;
    const int w    = blockIdx.x >> 4;
    const int head = blockIdx.x & 15;
    const int b    = w >> 6;
    const int h0   = ((w >> 3) & 7) * 7;
    const int w0c  = (w & 7) * 7;
    const int pixbase = b * 3136;

    // ---- pixel-row offset table ----
    if (tid < NKV) {
        int h, wc;
        if (tid < WA) { h = h0 + tid / 7; wc = w0c + tid % 7; }
        else {
            const int i = tid - WA;
            h = h0 + OFT.dr[i];  h += (h < 0) ? 56 : 0;  h -= (h >= 56) ? 56 : 0;
            wc = w0c + OFT.dc[i]; wc += (wc < 0) ? 56 : 0; wc -= (wc >= 56) ? 56 : 0;
        }
        pixt[tid] = (pixbase + h * 56 + wc) * QKVLD + head * HD;
    }
    __syncthreads();

    // ---- staging (u64 = 4 consecutive bf16 elems per load) ----
    for (int idx = tid; idx < WA * 8; idx += 256) {            // Q
        const int qi = idx >> 3, dq = idx & 7;
        *(u64*)(Qs + qi * QP + dq * 4) = *(const u64*)(qkvb + pixt[qi] + dq * 4);
    }
    for (int idx = tid; idx < NKV * 8; idx += 256) {           // K
        const int kv = idx >> 3, dq = idx & 7;
        *(u64*)(Ks + kv * KP + dq * 4) = *(const u64*)(qkvb + pixt[kv] + CDIM + dq * 4);
    }
    for (int idx = tid; idx < NKV * 8; idx += 256) {           // V -> Vt (transpose)
        const int kv = idx >> 3, dq = idx & 7;                 // d = dq*4 + j
        const u64 v = *(const u64*)(qkvb + pixt[kv] + 2 * CDIM + dq * 4);
        #pragma unroll
        for (int j = 0; j < 4; ++j)
            Vt[(dq * 4 + j) * VP + kv] = (u16)(v >> (16 * j));
    }
    // zero pads: Qs rows 49..63, Ks rows 181..191, Vt cols 181..191
    for (int idx = tid; idx < (64 - WA) * QP; idx += 256)
        Qs[WA * QP + idx] = 0;
    for (int idx = tid; idx < (NKVT - NKV) * KP; idx += 256)
        Ks[NKV * KP + idx] = 0;
    for (int idx = tid; idx < 32 * (NKVT - NKV); idx += 256)
        Vt[(idx / (NKVT - NKV)) * VP + NKV + idx % (NKVT - NKV)] = 0;
    __syncthreads();

    // ---- QK^T: wave wv owns q-rows [16wv, 16wv+16) ----
    const int lr = lane & 15;
    const int lk = (lane >> 4) * 8;
    const int qrow0 = 16 * wv + (lane >> 4) * 4;   // + r
    const short8 aq = *(const short8*)(Qs + (16 * wv + lr) * QP + lk);
    f32x4 s[12];
    #pragma unroll
    for (int n = 0; n < 12; ++n) {
        const short8 bk = *(const short8*)(Ks + (n * 16 + lr) * KP + lk);
        s[n] = __builtin_amdgcn_mfma_f32_16x16x32_bf16(aq, bk, (f32x4){0.f, 0.f, 0.f, 0.f}, 0, 0, 0);
    }

    // ---- scale + bias(+mask) via table: 12 coalesced float4 loads ----
    const float scale = 0.17677669529663687f;  // 32^-0.5
    const float* btb = bt + ((size_t)head * NKVT) * 64 + qrow0;
    #pragma unroll
    for (int n = 0; n < 12; ++n) {
        const float4 b4 = *(const float4*)(btb + (n * 16 + lr) * 64);
        s[n][0] = fmaf(s[n][0], scale, b4.x);
        s[n][1] = fmaf(s[n][1], scale, b4.y);
        s[n][2] = fmaf(s[n][2], scale, b4.z);
        s[n][3] = fmaf(s[n][3], scale, b4.w);
    }

    // ---- softmax in registers ----
    #pragma unroll
    for (int r = 0; r < 4; ++r) {
        float m = s[0][r];
        #pragma unroll
        for (int n = 1; n < 12; ++n) m = fmaxf(m, s[n][r]);
        #pragma unroll
        for (int off = 1; off <= 8; off <<= 1) m = fmaxf(m, __shfl_xor(m, off));
        float t = 0.f;
        #pragma unroll
        for (int n = 0; n < 12; ++n) { const float e = __expf(s[n][r] - m); s[n][r] = e; t += e; }
        #pragma unroll
        for (int off = 1; off <= 8; off <<= 1) t += __shfl_xor(t, off);
        const float inv = 1.f / t;
        #pragma unroll
        for (int n = 0; n < 12; ++n) s[n][r] *= inv;
    }

    __syncthreads();   // all waves' Ks reads retired before P overlays Ks

    // ---- PV in two kv-halves through the P overlay (wave-private rows) ----
    f32x4 o[2] = {{0.f, 0.f, 0.f, 0.f}, {0.f, 0.f, 0.f, 0.f}};
    #pragma unroll
    for (int half = 0; half < 2; ++half) {
        #pragma unroll
        for (int n = 0; n < 6; ++n)
            #pragma unroll
            for (int r = 0; r < 4; ++r)
                Ps[(qrow0 + r) * PP + n * 16 + lr] = f32_to_bf16(s[half * 6 + n][r]);
        #pragma unroll
        for (int kk = 0; kk < 3; ++kk) {
            const short8 pa = *(const short8*)(Ps + (16 * wv + lr) * PP + kk * 32 + lk);
            #pragma unroll
            for (int n0 = 0; n0 < 2; ++n0) {
                const short8 vb = *(const short8*)(Vt + (n0 * 16 + lr) * VP + (half * 3 + kk) * 32 + lk);
                o[n0] = __builtin_amdgcn_mfma_f32_16x16x32_bf16(pa, vb, o[n0], 0, 0, 0);
            }
        }
    }
    #pragma unroll
    for (int n0 = 0; n0 < 2; ++n0)
        #pragma unroll
        for (int r = 0; r < 4; ++r) {
            const int qi = qrow0 + r;
            if (qi < WA)
                aob[(size_t)(w * WA + qi) * CDIM + head * HD + n0 * 16 + lr] = f32_to_bf16(o[n0][r]);
        }
}

// ---------------- launch ----------------
extern "C" void kernel_launch(void* const* d_in, const int* in_sizes, int n_in,
                              void* d_out, int out_size, void* d_ws, size_t ws_size,
                              hipStream_t stream)
{
    const float* x      = (const float*)d_in[0];
    const float* qkv_w  = (const float*)d_in[1];
    const float* qkv_b  = (const float*)d_in[2];
    const float* proj_w = (const float*)d_in[3];
    const float* proj_b = (const float*)d_in[4];
    const float* rpbt   = (const float*)d_in[5];
    const float* rpbn   = (const float*)d_in[6];

    u16* xb   = (u16*)d_ws;                         // (25088, 512)
    u16* qkvb = xb + (size_t)NPIX * CDIM;           // (25088, 1536)
    u16* aob  = qkvb + (size_t)NPIX * QKVLD;        // (25088, 512)
    u16* qwb  = aob + (size_t)NPIX * CDIM;          // (1536, 512)
    u16* pwb  = qwb + (size_t)QKVLD * CDIM;         // (512, 512)
    float* bt = (float*)(pwb + (size_t)CDIM * CDIM);// (16, 192, 64)
    const size_t need = ((size_t)NPIX * CDIM + (size_t)NPIX * QKVLD + (size_t)NPIX * CDIM
                         + (size_t)QKVLD * CDIM + (size_t)CDIM * CDIM) * sizeof(u16)
                        + (size_t)NHEADS * NKVT * 64 * sizeof(float);
    if (ws_size < need) return;

    {
        const int nx = NPIX * CDIM;
        cvt_bf16<<<(nx / 4 + 255) / 256, 256, 0, stream>>>(x, xb, nx);
        const int nq = QKVLD * CDIM;
        cvt_bf16<<<(nq / 4 + 255) / 256, 256, 0, stream>>>(qkv_w, qwb, nq);
        const int np = CDIM * CDIM;
        cvt_bf16<<<(np / 4 + 255) / 256, 256, 0, stream>>>(proj_w, pwb, np);
        build_bias<<<(NHEADS * NKVT * 64) / 256, 256, 0, stream>>>(rpbt, rpbn, bt);
    }

    // QKV projection (bf16 out)
    gemm_mfma<true><<<dim3(QKVLD / 128, NPIX / 128), 256, 0, stream>>>(
        xb, qwb, qkv_b, qkvb, NPIX, QKVLD, CDIM);

    // windowed attention (bf16 out)
    attn_win<<<NWIN * NHEADS, 256, 0, stream>>>(qkvb, bt, aob);

    // output projection (fp32 out)
    gemm_mfma<false><<<dim3(CDIM / 128, NPIX / 128), 256, 0, stream>>>(
        aob, pwb, proj_b, d_out, NPIX, CDIM, CDIM);
}

// Round 9
// 226.897 us; speedup vs baseline: 8.3949x; 1.0096x over previous
//
#include <hip/hip_runtime.h>
#include <hip/hip_bf16.h>
#include <math.h>

typedef unsigned short u16;
typedef unsigned int   u32;
typedef unsigned long long u64;
typedef __attribute__((ext_vector_type(8))) short short8;   // 8 bf16 (4 VGPR)
typedef __attribute__((ext_vector_type(4))) float f32x4;

// ---------------- problem constants ----------------
#define NHEADS 16
#define HD     32
#define WA     49
#define NROLL  132
#define NKV    181     // WA + NROLL
#define NKVT   192     // 12 tiles of 16
#define CDIM   512
#define QKVLD  1536
#define NPIX   25088   // 8*56*56
#define NWIN   512
// LDS pitches (bf16 elems)
#define VP 200        // Vt pitch: 100 words/row, 100%32=4 -> 2-way max on b128 reads
#define PP 104        // Ps pitch: 52 words/row, 52%32=20 -> 2-way max

__device__ __forceinline__ u16 f32_to_bf16(float f) {
    union { float f; u32 u; } x; x.f = f;
    u32 r = x.u + 0x7FFFu + ((x.u >> 16) & 1u);   // RNE
    return (u16)(r >> 16);
}
__device__ __forceinline__ u16 cvt_bf16_hw(float f) {
    __hip_bfloat16 h = __float2bfloat16(f);       // RNE
    return *reinterpret_cast<u16*>(&h);
}

// ---------------- fp32 -> bf16 conversion ----------------
__global__ __launch_bounds__(256) void cvt_bf16(const float* __restrict__ in,
                                                u16* __restrict__ out, int n) {
    int i = (blockIdx.x * 256 + threadIdx.x) * 4;
    if (i >= n) return;
    float4 v = *(const float4*)(in + i);
    *(ushort4*)(out + i) = make_ushort4(f32_to_bf16(v.x), f32_to_bf16(v.y),
                                        f32_to_bf16(v.z), f32_to_bf16(v.w));
}

// ---------------- bias table: bt[16][192][64]  (head, kv, qi), mask baked in ----------------
__global__ __launch_bounds__(256) void build_bias(
    const float* __restrict__ rpbt,   // (169,16)
    const float* __restrict__ rpbn,   // (16,49,132)
    float* __restrict__ bt)
{
    const int idx = blockIdx.x * 256 + threadIdx.x;   // 16*192*64 = 196608
    const int h   = idx / (NKVT * 64);                // stride 12288 (NOT pow2)
    const int rem = idx - h * (NKVT * 64);
    const int kv  = rem >> 6;
    const int qi  = rem & 63;
    float v = -1e30f;
    if (qi < WA && kv < NKV) {
        if (kv < WA) {
            const int r1 = qi / 7, c1 = qi % 7, r2 = kv / 7, c2 = kv % 7;
            v = rpbt[((r1 - r2 + 6) * 13 + (c1 - c2 + 6)) * NHEADS + h];
        } else {
            v = rpbn[(h * WA + qi) * NROLL + (kv - WA)];
        }
    }
    bt[idx] = v;
}

// ---------------- bf16 MFMA GEMM: C = A @ W^T + bias ----------------
template<bool STORE_BF16>
__global__ __launch_bounds__(256) void gemm_mfma(
    const u16* __restrict__ A, const u16* __restrict__ W,
    const float* __restrict__ bias, void* __restrict__ Cv,
    int M, int N, int K)
{
    __shared__ __align__(16) u16 As[128 * 32];
    __shared__ __align__(16) u16 Bs[128 * 32];
    const int tid = threadIdx.x;
    const int lane = tid & 63, wv = tid >> 6;
    const int m0 = blockIdx.y * 128, n0 = blockIdx.x * 128;
    const int wr = (wv >> 1) * 64, wc = (wv & 1) * 64;
    const int lr = lane & 15;
    const int lk = (lane >> 4) * 8;
    const int srow = lane >> 2;
    const int scol = (lane & 3) * 8;

    f32x4 acc[4][4] = {};

    for (int k0 = 0; k0 < K; k0 += 32) {
        __syncthreads();
        #pragma unroll
        for (int blk = 0; blk < 2; ++blk) {
            const int r = wv * 32 + blk * 16;
            __builtin_amdgcn_global_load_lds(
                (const __attribute__((address_space(1))) void*)
                    (A + (size_t)(m0 + r + srow) * K + k0 + scol),
                (__attribute__((address_space(3))) void*)(As + r * 32), 16, 0, 0);
            __builtin_amdgcn_global_load_lds(
                (const __attribute__((address_space(1))) void*)
                    (W + (size_t)(n0 + r + srow) * K + k0 + scol),
                (__attribute__((address_space(3))) void*)(Bs + r * 32), 16, 0, 0);
        }
        __syncthreads();
        #pragma unroll
        for (int mi = 0; mi < 4; ++mi) {
            const short8 af = *(const short8*)(As + (wr + mi * 16 + lr) * 32 + lk);
            #pragma unroll
            for (int ni = 0; ni < 4; ++ni) {
                const short8 bf = *(const short8*)(Bs + (wc + ni * 16 + lr) * 32 + lk);
                acc[mi][ni] = __builtin_amdgcn_mfma_f32_16x16x32_bf16(af, bf, acc[mi][ni], 0, 0, 0);
            }
        }
    }

    const int col0 = n0 + wc + lr;
    #pragma unroll
    for (int ni = 0; ni < 4; ++ni) {
        const float bcol = bias[col0 + ni * 16];
        #pragma unroll
        for (int mi = 0; mi < 4; ++mi)
            #pragma unroll
            for (int r = 0; r < 4; ++r) {
                const int row = m0 + wr + mi * 16 + (lane >> 4) * 4 + r;
                const float v = acc[mi][ni][r] + bcol;
                if (STORE_BF16)
                    ((u16*)Cv)[(size_t)row * N + col0 + ni * 16] = f32_to_bf16(v);
                else
                    ((float*)Cv)[(size_t)row * N + col0 + ni * 16] = v;
            }
    }
}

// ---------------- rolled-neighbor offset table (np.nonzero order) ----------------
struct OffT { int dr[NROLL]; int dc[NROLL]; };
constexpr bool rvalid(int s, int r, int c) {
    return (s == 0) ? (r >= 4 || c >= 4) :
           (s == 1) ? (r >= 4 || c <= 2) :
           (s == 2) ? (r <= 2 || c >= 4) :
                      (r <= 2 || c <= 2);
}
constexpr OffT make_offt() {
    OffT t{};
    int p = 0;
    for (int s = 0; s < 4; ++s)
        for (int r = 0; r < 7; ++r)
            for (int c = 0; c < 7; ++c)
                if (rvalid(s, r, c)) {
                    const int sh = (s < 2) ? -3 : 3;
                    const int sw = (s & 1) ? 3 : -3;
                    t.dr[p] = r - sh;   // rolled[h] = orig[h - sh]
                    t.dc[p] = c - sw;
                    ++p;
                }
    return t;
}
__device__ constexpr OffT OFT = make_offt();

// ---------------- MFMA window attention ----------------
// K and Q fragments come straight from global (contiguous 16B per lane);
// only V (needs transpose) and P (needs redistribution) go through LDS.
__global__ __launch_bounds__(256, 5) void attn_win(
    const u16* __restrict__ qkvb,    // (25088, 1536) bf16: q|k|v
    const float* __restrict__ bt,    // (16, 192, 64) bias table, mask baked
    u16* __restrict__ aob)           // (25088, 512) bf16
{
    // Vt 12800 + Ps 13312 + pixt 724 = 26,836 B  -> up to 6 blocks/CU
    __shared__ __align__(16) u16 Vt[32 * VP];   // V transposed: [d][kv]
    __shared__ __align__(16) u16 Ps[64 * PP];   // P bf16: [qi][96-col halves]
    __shared__ int pixt[NKV];

    const int tid  = threadIdx.x;
    const int lane = tid & 63, wv = tid >> 6;
    const int w    = blockIdx.x >> 4;
    const int head = blockIdx.x & 15;
    const int b    = w >> 6;
    const int h0   = ((w >> 3) & 7) * 7;
    const int w0c  = (w & 7) * 7;
    const int pixbase = b * 3136;

    // ---- pixel-row offset table ----
    if (tid < NKV) {
        int h, wc;
        if (tid < WA) { h = h0 + tid / 7; wc = w0c + tid % 7; }
        else {
            const int i = tid - WA;
            h = h0 + OFT.dr[i];  h += (h < 0) ? 56 : 0;  h -= (h >= 56) ? 56 : 0;
            wc = w0c + OFT.dc[i]; wc += (wc < 0) ? 56 : 0; wc -= (wc >= 56) ? 56 : 0;
        }
        pixt[tid] = (pixbase + h * 56 + wc) * QKVLD + head * HD;
    }
    __syncthreads();

    const int lr = lane & 15;
    const int lk = (lane >> 4) * 8;
    const int qrow0 = 16 * wv + (lane >> 4) * 4;   // + r

    // ---- Q fragment + 12 K fragments direct from global ----
    const int qr = 16 * wv + lr;
    const short8 aq = *(const short8*)(qkvb + pixt[(qr < WA) ? qr : 0] + lk);
    short8 bk[12];
    #pragma unroll
    for (int n = 0; n < 12; ++n) {
        const int kvr = n * 16 + lr;
        bk[n] = *(const short8*)(qkvb + pixt[(kvr < NKV) ? kvr : 0] + CDIM + lk);
        if (kvr >= NKV) bk[n] = (short8){0, 0, 0, 0, 0, 0, 0, 0};  // keep max clean
    }

    // ---- V staging -> Vt (transpose) + zero-pad cols 181..191 ----
    for (int idx = tid; idx < NKV * 8; idx += 256) {
        const int kv = idx >> 3, dq = idx & 7;                 // d = dq*4 + j
        const u64 v = *(const u64*)(qkvb + pixt[kv] + 2 * CDIM + dq * 4);
        #pragma unroll
        for (int j = 0; j < 4; ++j)
            Vt[(dq * 4 + j) * VP + kv] = (u16)(v >> (16 * j));
    }
    for (int idx = tid; idx < 32 * (NKVT - NKV); idx += 256)
        Vt[(idx / (NKVT - NKV)) * VP + NKV + idx % (NKVT - NKV)] = 0;

    // ---- QK^T (no LDS involved) ----
    f32x4 s[12];
    #pragma unroll
    for (int n = 0; n < 12; ++n)
        s[n] = __builtin_amdgcn_mfma_f32_16x16x32_bf16(aq, bk[n], (f32x4){0.f, 0.f, 0.f, 0.f}, 0, 0, 0);

    // ---- scale + bias(+mask) via table: 12 coalesced float4 loads ----
    const float scale = 0.17677669529663687f;  // 32^-0.5
    const float* btb = bt + ((size_t)head * NKVT) * 64 + qrow0;
    #pragma unroll
    for (int n = 0; n < 12; ++n) {
        const float4 b4 = *(const float4*)(btb + (n * 16 + lr) * 64);
        s[n][0] = fmaf(s[n][0], scale, b4.x);
        s[n][1] = fmaf(s[n][1], scale, b4.y);
        s[n][2] = fmaf(s[n][2], scale, b4.z);
        s[n][3] = fmaf(s[n][3], scale, b4.w);
    }

    // ---- softmax in registers ----
    #pragma unroll
    for (int r = 0; r < 4; ++r) {
        float m = s[0][r];
        #pragma unroll
        for (int n = 1; n < 12; ++n) m = fmaxf(m, s[n][r]);
        #pragma unroll
        for (int off = 1; off <= 8; off <<= 1) m = fmaxf(m, __shfl_xor(m, off));
        float t = 0.f;
        #pragma unroll
        for (int n = 0; n < 12; ++n) { const float e = __expf(s[n][r] - m); s[n][r] = e; t += e; }
        #pragma unroll
        for (int off = 1; off <= 8; off <<= 1) t += __shfl_xor(t, off);
        const float inv = 1.f / t;
        #pragma unroll
        for (int n = 0; n < 12; ++n) s[n][r] *= inv;
    }

    __syncthreads();   // Vt staging complete before PV reads

    // ---- P -> LDS (wave-private rows, no barrier) in two col-halves of 96 ----
    f32x4 o[2] = {{0.f, 0.f, 0.f, 0.f}, {0.f, 0.f, 0.f, 0.f}};
    #pragma unroll
    for (int half = 0; half < 2; ++half) {
        #pragma unroll
        for (int n = 0; n < 6; ++n)
            #pragma unroll
            for (int r = 0; r < 4; ++r)
                Ps[(qrow0 + r) * PP + n * 16 + lr] = cvt_bf16_hw(s[half * 6 + n][r]);
        #pragma unroll
        for (int kk = 0; kk < 3; ++kk) {
            const short8 pa = *(const short8*)(Ps + (16 * wv + lr) * PP + kk * 32 + lk);
            #pragma unroll
            for (int n0 = 0; n0 < 2; ++n0) {
                const short8 vb = *(const short8*)(Vt + (n0 * 16 + lr) * VP + (half * 3 + kk) * 32 + lk);
                o[n0] = __builtin_amdgcn_mfma_f32_16x16x32_bf16(pa, vb, o[n0], 0, 0, 0);
            }
        }
    }
    #pragma unroll
    for (int n0 = 0; n0 < 2; ++n0)
        #pragma unroll
        for (int r = 0; r < 4; ++r) {
            const int qi = qrow0 + r;
            if (qi < WA)
                aob[(size_t)(w * WA + qi) * CDIM + head * HD + n0 * 16 + lr] = cvt_bf16_hw(o[n0][r]);
        }
}

// ---------------- launch ----------------
extern "C" void kernel_launch(void* const* d_in, const int* in_sizes, int n_in,
                              void* d_out, int out_size, void* d_ws, size_t ws_size,
                              hipStream_t stream)
{
    const float* x      = (const float*)d_in[0];
    const float* qkv_w  = (const float*)d_in[1];
    const float* qkv_b  = (const float*)d_in[2];
    const float* proj_w = (const float*)d_in[3];
    const float* proj_b = (const float*)d_in[4];
    const float* rpbt   = (const float*)d_in[5];
    const float* rpbn   = (const float*)d_in[6];

    u16* xb   = (u16*)d_ws;                         // (25088, 512)
    u16* qkvb = xb + (size_t)NPIX * CDIM;           // (25088, 1536)
    u16* aob  = qkvb + (size_t)NPIX * QKVLD;        // (25088, 512)
    u16* qwb  = aob + (size_t)NPIX * CDIM;          // (1536, 512)
    u16* pwb  = qwb + (size_t)QKVLD * CDIM;         // (512, 512)
    float* bt = (float*)(pwb + (size_t)CDIM * CDIM);// (16, 192, 64)
    const size_t need = ((size_t)NPIX * CDIM + (size_t)NPIX * QKVLD + (size_t)NPIX * CDIM
                         + (size_t)QKVLD * CDIM + (size_t)CDIM * CDIM) * sizeof(u16)
                        + (size_t)NHEADS * NKVT * 64 * sizeof(float);
    if (ws_size < need) return;

    {
        const int nx = NPIX * CDIM;
        cvt_bf16<<<(nx / 4 + 255) / 256, 256, 0, stream>>>(x, xb, nx);
        const int nq = QKVLD * CDIM;
        cvt_bf16<<<(nq / 4 + 255) / 256, 256, 0, stream>>>(qkv_w, qwb, nq);
        const int np = CDIM * CDIM;
        cvt_bf16<<<(np / 4 + 255) / 256, 256, 0, stream>>>(proj_w, pwb, np);
        build_bias<<<(NHEADS * NKVT * 64) / 256, 256, 0, stream>>>(rpbt, rpbn, bt);
    }

    // QKV projection (bf16 out)
    gemm_mfma<true><<<dim3(QKVLD / 128, NPIX / 128), 256, 0, stream>>>(
        xb, qwb, qkv_b, qkvb, NPIX, QKVLD, CDIM);

    // windowed attention (bf16 out)
    attn_win<<<NWIN * NHEADS, 256, 0, stream>>>(qkvb, bt, aob);

    // output projection (fp32 out)
    gemm_mfma<false><<<dim3(CDIM / 128, NPIX / 128), 256, 0, stream>>>(
        aob, pwb, proj_b, d_out, NPIX, CDIM, CDIM);
}

// Round 10
// 216.602 us; speedup vs baseline: 8.7939x; 1.0475x over previous
//
#include <hip/hip_runtime.h>
#include <hip/hip_bf16.h>
#include <math.h>

typedef unsigned short u16;
typedef unsigned int   u32;
typedef unsigned long long u64;
typedef __attribute__((ext_vector_type(8))) short short8;   // 8 bf16 (4 VGPR)
typedef __attribute__((ext_vector_type(4))) float f32x4;

// ---------------- problem constants ----------------
#define NHEADS 16
#define HD     32
#define WA     49
#define NROLL  132
#define NKV    181     // WA + NROLL
#define NKVT   192     // 12 tiles of 16
#define CDIM   512
#define QKVLD  1536
#define NPIX   25088   // 8*56*56
#define NWIN   512
// LDS pitches (bf16 elems)
#define VP 200        // Vt pitch
#define PP 104        // Ps pitch

__device__ __forceinline__ u16 f32_to_bf16(float f) {
    union { float f; u32 u; } x; x.f = f;
    u32 r = x.u + 0x7FFFu + ((x.u >> 16) & 1u);   // RNE
    return (u16)(r >> 16);
}
__device__ __forceinline__ u16 cvt_bf16_hw(float f) {
    __hip_bfloat16 h = __float2bfloat16(f);       // RNE
    return *reinterpret_cast<u16*>(&h);
}

// ---------------- fp32 -> bf16 conversion ----------------
__global__ __launch_bounds__(256) void cvt_bf16(const float* __restrict__ in,
                                                u16* __restrict__ out, int n) {
    int i = (blockIdx.x * 256 + threadIdx.x) * 4;
    if (i >= n) return;
    float4 v = *(const float4*)(in + i);
    *(ushort4*)(out + i) = make_ushort4(f32_to_bf16(v.x), f32_to_bf16(v.y),
                                        f32_to_bf16(v.z), f32_to_bf16(v.w));
}

// ---------------- bias table, MFMA C-fragment order ----------------
// bt[head][qtile(4)][ktile(12)][lane(64)][r(4)]  = 16*4*12*64*4 = 196608 floats.
// qi = qtile*16 + (lane>>4)*4 + r ; kv = ktile*16 + (lane&15). Mask baked (-1e30).
__global__ __launch_bounds__(256) void build_bias(
    const float* __restrict__ rpbt,   // (169,16)
    const float* __restrict__ rpbn,   // (16,49,132)
    float* __restrict__ bt)
{
    const int idx  = blockIdx.x * 256 + threadIdx.x;
    const int h    = idx / 12288;            // 4*12*64*4
    const int rem  = idx % 12288;
    const int qt   = rem / 3072;             // 12*64*4
    const int rem2 = rem % 3072;
    const int n    = rem2 / 256;             // 64*4
    const int rem3 = rem2 % 256;
    const int lane = rem3 / 4;
    const int r    = rem3 % 4;
    const int qi = qt * 16 + (lane >> 4) * 4 + r;
    const int kv = n * 16 + (lane & 15);
    float v = -1e30f;
    if (qi < WA && kv < NKV) {
        if (kv < WA) {
            const int r1 = qi / 7, c1 = qi % 7, r2 = kv / 7, c2 = kv % 7;
            v = rpbt[((r1 - r2 + 6) * 13 + (c1 - c2 + 6)) * NHEADS + h];
        } else {
            v = rpbn[(h * WA + qi) * NROLL + (kv - WA)];
        }
    }
    bt[idx] = v;
}

// ---------------- bf16 MFMA GEMM: C = A @ W^T + bias ----------------
template<bool STORE_BF16>
__global__ __launch_bounds__(256) void gemm_mfma(
    const u16* __restrict__ A, const u16* __restrict__ W,
    const float* __restrict__ bias, void* __restrict__ Cv,
    int M, int N, int K)
{
    __shared__ __align__(16) u16 As[128 * 32];
    __shared__ __align__(16) u16 Bs[128 * 32];
    const int tid = threadIdx.x;
    const int lane = tid & 63, wv = tid >> 6;
    const int m0 = blockIdx.y * 128, n0 = blockIdx.x * 128;
    const int wr = (wv >> 1) * 64, wc = (wv & 1) * 64;
    const int lr = lane & 15;
    const int lk = (lane >> 4) * 8;
    const int srow = lane >> 2;
    const int scol = (lane & 3) * 8;

    f32x4 acc[4][4] = {};

    for (int k0 = 0; k0 < K; k0 += 32) {
        __syncthreads();
        #pragma unroll
        for (int blk = 0; blk < 2; ++blk) {
            const int r = wv * 32 + blk * 16;
            __builtin_amdgcn_global_load_lds(
                (const __attribute__((address_space(1))) void*)
                    (A + (size_t)(m0 + r + srow) * K + k0 + scol),
                (__attribute__((address_space(3))) void*)(As + r * 32), 16, 0, 0);
            __builtin_amdgcn_global_load_lds(
                (const __attribute__((address_space(1))) void*)
                    (W + (size_t)(n0 + r + srow) * K + k0 + scol),
                (__attribute__((address_space(3))) void*)(Bs + r * 32), 16, 0, 0);
        }
        __syncthreads();
        #pragma unroll
        for (int mi = 0; mi < 4; ++mi) {
            const short8 af = *(const short8*)(As + (wr + mi * 16 + lr) * 32 + lk);
            #pragma unroll
            for (int ni = 0; ni < 4; ++ni) {
                const short8 bf = *(const short8*)(Bs + (wc + ni * 16 + lr) * 32 + lk);
                acc[mi][ni] = __builtin_amdgcn_mfma_f32_16x16x32_bf16(af, bf, acc[mi][ni], 0, 0, 0);
            }
        }
    }

    const int col0 = n0 + wc + lr;
    #pragma unroll
    for (int ni = 0; ni < 4; ++ni) {
        const float bcol = bias[col0 + ni * 16];
        #pragma unroll
        for (int mi = 0; mi < 4; ++mi)
            #pragma unroll
            for (int r = 0; r < 4; ++r) {
                const int row = m0 + wr + mi * 16 + (lane >> 4) * 4 + r;
                const float v = acc[mi][ni][r] + bcol;
                if (STORE_BF16)
                    ((u16*)Cv)[(size_t)row * N + col0 + ni * 16] = f32_to_bf16(v);
                else
                    ((float*)Cv)[(size_t)row * N + col0 + ni * 16] = v;
            }
    }
}

// ---------------- rolled-neighbor offset table (np.nonzero order) ----------------
struct OffT { int dr[NROLL]; int dc[NROLL]; };
constexpr bool rvalid(int s, int r, int c) {
    return (s == 0) ? (r >= 4 || c >= 4) :
           (s == 1) ? (r >= 4 || c <= 2) :
           (s == 2) ? (r <= 2 || c >= 4) :
                      (r <= 2 || c <= 2);
}
constexpr OffT make_offt() {
    OffT t{};
    int p = 0;
    for (int s = 0; s < 4; ++s)
        for (int r = 0; r < 7; ++r)
            for (int c = 0; c < 7; ++c)
                if (rvalid(s, r, c)) {
                    const int sh = (s < 2) ? -3 : 3;
                    const int sw = (s & 1) ? 3 : -3;
                    t.dr[p] = r - sh;   // rolled[h] = orig[h - sh]
                    t.dc[p] = c - sw;
                    ++p;
                }
    return t;
}
__device__ constexpr OffT OFT = make_offt();

// ---------------- MFMA window attention ----------------
// Q/K fragments direct from global; V via LDS transpose; P via LDS; bias via
// fragment-ordered table (coalesced float4 per lane).
__global__ __launch_bounds__(256, 6) void attn_win(
    const u16* __restrict__ qkvb,    // (25088, 1536) bf16: q|k|v
    const float* __restrict__ bt,    // fragment-ordered bias table
    u16* __restrict__ aob)           // (25088, 512) bf16
{
    // Vt 12800 + Ps 13312 + pixt 724 = 26,836 B  -> 6 blocks/CU
    __shared__ __align__(16) u16 Vt[32 * VP];   // V transposed: [d][kv]
    __shared__ __align__(16) u16 Ps[64 * PP];   // P bf16 (two 96-col halves)
    __shared__ int pixt[NKV];

    const int tid  = threadIdx.x;
    const int lane = tid & 63, wv = tid >> 6;
    const int w    = blockIdx.x >> 4;
    const int head = blockIdx.x & 15;
    const int b    = w >> 6;
    const int h0   = ((w >> 3) & 7) * 7;
    const int w0c  = (w & 7) * 7;
    const int pixbase = b * 3136;

    // ---- pixel-row offset table ----
    if (tid < NKV) {
        int h, wc;
        if (tid < WA) { h = h0 + tid / 7; wc = w0c + tid % 7; }
        else {
            const int i = tid - WA;
            h = h0 + OFT.dr[i];  h += (h < 0) ? 56 : 0;  h -= (h >= 56) ? 56 : 0;
            wc = w0c + OFT.dc[i]; wc += (wc < 0) ? 56 : 0; wc -= (wc >= 56) ? 56 : 0;
        }
        pixt[tid] = (pixbase + h * 56 + wc) * QKVLD + head * HD;
    }
    __syncthreads();

    const int lr = lane & 15;
    const int lk = (lane >> 4) * 8;
    const int qrow0 = 16 * wv + (lane >> 4) * 4;   // + r

    // ---- Q fragment + 12 K fragments direct from global ----
    const int qr = 16 * wv + lr;
    const short8 aq = *(const short8*)(qkvb + pixt[(qr < WA) ? qr : 0] + lk);
    short8 bk[12];
    #pragma unroll
    for (int n = 0; n < 12; ++n) {
        const int kvr = n * 16 + lr;
        bk[n] = *(const short8*)(qkvb + pixt[(kvr < NKV) ? kvr : 0] + CDIM + lk);
        if (kvr >= NKV) bk[n] = (short8){0, 0, 0, 0, 0, 0, 0, 0};  // keep max clean
    }

    // ---- V staging -> Vt (transpose) + zero-pad cols 181..191 ----
    for (int idx = tid; idx < NKV * 8; idx += 256) {
        const int kv = idx >> 3, dq = idx & 7;                 // d = dq*4 + j
        const u64 v = *(const u64*)(qkvb + pixt[kv] + 2 * CDIM + dq * 4);
        #pragma unroll
        for (int j = 0; j < 4; ++j)
            Vt[(dq * 4 + j) * VP + kv] = (u16)(v >> (16 * j));
    }
    for (int idx = tid; idx < 32 * (NKVT - NKV); idx += 256)
        Vt[(idx / (NKVT - NKV)) * VP + NKV + idx % (NKVT - NKV)] = 0;

    // ---- QK^T (no LDS involved) ----
    f32x4 s[12];
    #pragma unroll
    for (int n = 0; n < 12; ++n)
        s[n] = __builtin_amdgcn_mfma_f32_16x16x32_bf16(aq, bk[n], (f32x4){0.f, 0.f, 0.f, 0.f}, 0, 0, 0);

    // ---- scale + bias(+mask): fragment-ordered table, coalesced float4 ----
    const float scale = 0.17677669529663687f;  // 32^-0.5
    const float* btb = bt + (((size_t)head * 4 + wv) * 12) * 256 + lane * 4;
    #pragma unroll
    for (int n = 0; n < 12; ++n) {
        const float4 b4 = *(const float4*)(btb + n * 256);
        s[n][0] = fmaf(s[n][0], scale, b4.x);
        s[n][1] = fmaf(s[n][1], scale, b4.y);
        s[n][2] = fmaf(s[n][2], scale, b4.z);
        s[n][3] = fmaf(s[n][3], scale, b4.w);
    }

    // ---- softmax in registers ----
    #pragma unroll
    for (int r = 0; r < 4; ++r) {
        float m = s[0][r];
        #pragma unroll
        for (int n = 1; n < 12; ++n) m = fmaxf(m, s[n][r]);
        #pragma unroll
        for (int off = 1; off <= 8; off <<= 1) m = fmaxf(m, __shfl_xor(m, off));
        float t = 0.f;
        #pragma unroll
        for (int n = 0; n < 12; ++n) { const float e = __expf(s[n][r] - m); s[n][r] = e; t += e; }
        #pragma unroll
        for (int off = 1; off <= 8; off <<= 1) t += __shfl_xor(t, off);
        const float inv = 1.f / t;
        #pragma unroll
        for (int n = 0; n < 12; ++n) s[n][r] *= inv;
    }

    __syncthreads();   // Vt staging complete before PV reads

    // ---- P -> LDS (wave-private rows) in two col-halves of 96 ----
    f32x4 o[2] = {{0.f, 0.f, 0.f, 0.f}, {0.f, 0.f, 0.f, 0.f}};
    #pragma unroll
    for (int half = 0; half < 2; ++half) {
        #pragma unroll
        for (int n = 0; n < 6; ++n)
            #pragma unroll
            for (int r = 0; r < 4; ++r)
                Ps[(qrow0 + r) * PP + n * 16 + lr] = cvt_bf16_hw(s[half * 6 + n][r]);
        #pragma unroll
        for (int kk = 0; kk < 3; ++kk) {
            const short8 pa = *(const short8*)(Ps + (16 * wv + lr) * PP + kk * 32 + lk);
            #pragma unroll
            for (int n0 = 0; n0 < 2; ++n0) {
                const short8 vb = *(const short8*)(Vt + (n0 * 16 + lr) * VP + (half * 3 + kk) * 32 + lk);
                o[n0] = __builtin_amdgcn_mfma_f32_16x16x32_bf16(pa, vb, o[n0], 0, 0, 0);
            }
        }
    }
    #pragma unroll
    for (int n0 = 0; n0 < 2; ++n0)
        #pragma unroll
        for (int r = 0; r < 4; ++r) {
            const int qi = qrow0 + r;
            if (qi < WA)
                aob[(size_t)(w * WA + qi) * CDIM + head * HD + n0 * 16 + lr] = cvt_bf16_hw(o[n0][r]);
        }
}

// ---------------- launch ----------------
extern "C" void kernel_launch(void* const* d_in, const int* in_sizes, int n_in,
                              void* d_out, int out_size, void* d_ws, size_t ws_size,
                              hipStream_t stream)
{
    const float* x      = (const float*)d_in[0];
    const float* qkv_w  = (const float*)d_in[1];
    const float* qkv_b  = (const float*)d_in[2];
    const float* proj_w = (const float*)d_in[3];
    const float* proj_b = (const float*)d_in[4];
    const float* rpbt   = (const float*)d_in[5];
    const float* rpbn   = (const float*)d_in[6];

    u16* xb   = (u16*)d_ws;                         // (25088, 512)
    u16* qkvb = xb + (size_t)NPIX * CDIM;           // (25088, 1536)
    u16* aob  = qkvb + (size_t)NPIX * QKVLD;        // (25088, 512)
    u16* qwb  = aob + (size_t)NPIX * CDIM;          // (1536, 512)
    u16* pwb  = qwb + (size_t)QKVLD * CDIM;         // (512, 512)
    float* bt = (float*)(pwb + (size_t)CDIM * CDIM);// 196608 floats
    const size_t need = ((size_t)NPIX * CDIM + (size_t)NPIX * QKVLD + (size_t)NPIX * CDIM
                         + (size_t)QKVLD * CDIM + (size_t)CDIM * CDIM) * sizeof(u16)
                        + (size_t)NHEADS * NKVT * 64 * sizeof(float);
    if (ws_size < need) return;

    {
        const int nx = NPIX * CDIM;
        cvt_bf16<<<(nx / 4 + 255) / 256, 256, 0, stream>>>(x, xb, nx);
        const int nq = QKVLD * CDIM;
        cvt_bf16<<<(nq / 4 + 255) / 256, 256, 0, stream>>>(qkv_w, qwb, nq);
        const int np = CDIM * CDIM;
        cvt_bf16<<<(np / 4 + 255) / 256, 256, 0, stream>>>(proj_w, pwb, np);
        build_bias<<<(NHEADS * NKVT * 64) / 256, 256, 0, stream>>>(rpbt, rpbn, bt);
    }

    // QKV projection (bf16 out)
    gemm_mfma<true><<<dim3(QKVLD / 128, NPIX / 128), 256, 0, stream>>>(
        xb, qwb, qkv_b, qkvb, NPIX, QKVLD, CDIM);

    // windowed attention (bf16 out)
    attn_win<<<NWIN * NHEADS, 256, 0, stream>>>(qkvb, bt, aob);

    // output projection (fp32 out)
    gemm_mfma<false><<<dim3(CDIM / 128, NPIX / 128), 256, 0, stream>>>(
        aob, pwb, proj_b, d_out, NPIX, CDIM, CDIM);
}

// Round 11
// 208.808 us; speedup vs baseline: 9.1222x; 1.0373x over previous
//
#include <hip/hip_runtime.h>
#include <hip/hip_bf16.h>
#include <math.h>

typedef unsigned short u16;
typedef unsigned int   u32;
typedef unsigned long long u64;
typedef __attribute__((ext_vector_type(8))) short short8;   // 8 bf16 (4 VGPR)
typedef __attribute__((ext_vector_type(4))) float f32x4;

// ---------------- problem constants ----------------
#define NHEADS 16
#define HD     32
#define WA     49
#define NROLL  132
#define NKV    181     // WA + NROLL
#define NKVT   192     // 12 tiles of 16
#define CDIM   512
#define QKVLD  1536
#define NPIX   25088   // 8*56*56
#define NWIN   512
// LDS pitches (bf16 elems)
#define VP 200        // Vt pitch
#define PP 104        // Ps pitch (96 cols + 8 pad; 208B row, 16B-aligned)

__device__ __forceinline__ u16 f32_to_bf16(float f) {
    union { float f; u32 u; } x; x.f = f;
    u32 r = x.u + 0x7FFFu + ((x.u >> 16) & 1u);   // RNE
    return (u16)(r >> 16);
}
__device__ __forceinline__ u16 cvt_bf16_hw(float f) {
    __hip_bfloat16 h = __float2bfloat16(f);       // RNE
    return *reinterpret_cast<u16*>(&h);
}

// ---------------- fp32 -> bf16 conversion ----------------
__global__ __launch_bounds__(256) void cvt_bf16(const float* __restrict__ in,
                                                u16* __restrict__ out, int n) {
    int i = (blockIdx.x * 256 + threadIdx.x) * 4;
    if (i >= n) return;
    float4 v = *(const float4*)(in + i);
    *(ushort4*)(out + i) = make_ushort4(f32_to_bf16(v.x), f32_to_bf16(v.y),
                                        f32_to_bf16(v.z), f32_to_bf16(v.w));
}

// ---------------- bias table, swapped-QK^T C-fragment order ----------------
// bt[head][qt(4)][n(12)][lane(64)][r(4)], where for the SWAPPED mfma(K,Q):
//   qi = qt*16 + (lane&15)            (C column)
//   kv = n*16 + (lane>>4)*4 + r       (C row)
// Mask baked: -1e30 outside qi<49 / kv<181.
__global__ __launch_bounds__(256) void build_bias(
    const float* __restrict__ rpbt,   // (169,16)
    const float* __restrict__ rpbn,   // (16,49,132)
    float* __restrict__ bt)
{
    const int idx  = blockIdx.x * 256 + threadIdx.x;
    const int h    = idx / 12288;            // 4*12*64*4
    const int rem  = idx % 12288;
    const int qt   = rem / 3072;             // 12*64*4
    const int rem2 = rem % 3072;
    const int n    = rem2 / 256;             // 64*4
    const int rem3 = rem2 % 256;
    const int lane = rem3 / 4;
    const int r    = rem3 % 4;
    const int qi = qt * 16 + (lane & 15);
    const int kv = n * 16 + (lane >> 4) * 4 + r;
    float v = -1e30f;
    if (qi < WA && kv < NKV) {
        if (kv < WA) {
            const int r1 = qi / 7, c1 = qi % 7, r2 = kv / 7, c2 = kv % 7;
            v = rpbt[((r1 - r2 + 6) * 13 + (c1 - c2 + 6)) * NHEADS + h];
        } else {
            v = rpbn[(h * WA + qi) * NROLL + (kv - WA)];
        }
    }
    bt[idx] = v;
}

// ---------------- bf16 MFMA GEMM: C = A @ W^T + bias ----------------
template<bool STORE_BF16>
__global__ __launch_bounds__(256) void gemm_mfma(
    const u16* __restrict__ A, const u16* __restrict__ W,
    const float* __restrict__ bias, void* __restrict__ Cv,
    int M, int N, int K)
{
    __shared__ __align__(16) u16 As[128 * 32];
    __shared__ __align__(16) u16 Bs[128 * 32];
    const int tid = threadIdx.x;
    const int lane = tid & 63, wv = tid >> 6;
    const int m0 = blockIdx.y * 128, n0 = blockIdx.x * 128;
    const int wr = (wv >> 1) * 64, wc = (wv & 1) * 64;
    const int lr = lane & 15;
    const int lk = (lane >> 4) * 8;
    const int srow = lane >> 2;
    const int scol = (lane & 3) * 8;

    f32x4 acc[4][4] = {};

    for (int k0 = 0; k0 < K; k0 += 32) {
        __syncthreads();
        #pragma unroll
        for (int blk = 0; blk < 2; ++blk) {
            const int r = wv * 32 + blk * 16;
            __builtin_amdgcn_global_load_lds(
                (const __attribute__((address_space(1))) void*)
                    (A + (size_t)(m0 + r + srow) * K + k0 + scol),
                (__attribute__((address_space(3))) void*)(As + r * 32), 16, 0, 0);
            __builtin_amdgcn_global_load_lds(
                (const __attribute__((address_space(1))) void*)
                    (W + (size_t)(n0 + r + srow) * K + k0 + scol),
                (__attribute__((address_space(3))) void*)(Bs + r * 32), 16, 0, 0);
        }
        __syncthreads();
        #pragma unroll
        for (int mi = 0; mi < 4; ++mi) {
            const short8 af = *(const short8*)(As + (wr + mi * 16 + lr) * 32 + lk);
            #pragma unroll
            for (int ni = 0; ni < 4; ++ni) {
                const short8 bf = *(const short8*)(Bs + (wc + ni * 16 + lr) * 32 + lk);
                acc[mi][ni] = __builtin_amdgcn_mfma_f32_16x16x32_bf16(af, bf, acc[mi][ni], 0, 0, 0);
            }
        }
    }

    const int col0 = n0 + wc + lr;
    #pragma unroll
    for (int ni = 0; ni < 4; ++ni) {
        const float bcol = bias[col0 + ni * 16];
        #pragma unroll
        for (int mi = 0; mi < 4; ++mi)
            #pragma unroll
            for (int r = 0; r < 4; ++r) {
                const int row = m0 + wr + mi * 16 + (lane >> 4) * 4 + r;
                const float v = acc[mi][ni][r] + bcol;
                if (STORE_BF16)
                    ((u16*)Cv)[(size_t)row * N + col0 + ni * 16] = f32_to_bf16(v);
                else
                    ((float*)Cv)[(size_t)row * N + col0 + ni * 16] = v;
            }
    }
}

// ---------------- rolled-neighbor offset table (np.nonzero order) ----------------
struct OffT { int dr[NROLL]; int dc[NROLL]; };
constexpr bool rvalid(int s, int r, int c) {
    return (s == 0) ? (r >= 4 || c >= 4) :
           (s == 1) ? (r >= 4 || c <= 2) :
           (s == 2) ? (r <= 2 || c >= 4) :
                      (r <= 2 || c <= 2);
}
constexpr OffT make_offt() {
    OffT t{};
    int p = 0;
    for (int s = 0; s < 4; ++s)
        for (int r = 0; r < 7; ++r)
            for (int c = 0; c < 7; ++c)
                if (rvalid(s, r, c)) {
                    const int sh = (s < 2) ? -3 : 3;
                    const int sw = (s & 1) ? 3 : -3;
                    t.dr[p] = r - sh;   // rolled[h] = orig[h - sh]
                    t.dc[p] = c - sw;
                    ++p;
                }
    return t;
}
__device__ constexpr OffT OFT = make_offt();

// ---------------- MFMA window attention (swapped QK^T) ----------------
// mfma(K,Q): each lane owns ONE q-row (q=16wv+(lane&15)); kv = n*16+hi*4+r.
// Softmax reduce = 2 shfl (16,32); P packs 4 consecutive kv -> ds_write_b64.
__global__ __launch_bounds__(256, 6) void attn_win(
    const u16* __restrict__ qkvb,    // (25088, 1536) bf16: q|k|v
    const float* __restrict__ bt,    // swapped-fragment bias table
    u16* __restrict__ aob)           // (25088, 512) bf16
{
    // Vt 12800 + Ps 13312 + pixt 724 = 26,836 B  -> 6 blocks/CU
    __shared__ __align__(16) u16 Vt[32 * VP];   // V transposed: [d][kv]
    __shared__ __align__(16) u16 Ps[64 * PP];   // P bf16 (two 96-col halves)
    __shared__ int pixt[NKV];

    const int tid  = threadIdx.x;
    const int lane = tid & 63, wv = tid >> 6;
    const int w    = blockIdx.x >> 4;
    const int head = blockIdx.x & 15;
    const int b    = w >> 6;
    const int h0   = ((w >> 3) & 7) * 7;
    const int w0c  = (w & 7) * 7;
    const int pixbase = b * 3136;

    // ---- pixel-row offset table ----
    if (tid < NKV) {
        int h, wc;
        if (tid < WA) { h = h0 + tid / 7; wc = w0c + tid % 7; }
        else {
            const int i = tid - WA;
            h = h0 + OFT.dr[i];  h += (h < 0) ? 56 : 0;  h -= (h >= 56) ? 56 : 0;
            wc = w0c + OFT.dc[i]; wc += (wc < 0) ? 56 : 0; wc -= (wc >= 56) ? 56 : 0;
        }
        pixt[tid] = (pixbase + h * 56 + wc) * QKVLD + head * HD;
    }
    __syncthreads();

    const int lr = lane & 15;
    const int lk = (lane >> 4) * 8;
    const int qrow0 = 16 * wv + (lane >> 4) * 4;   // + r (PV output rows)

    // ---- Q fragment + 12 K fragments direct from global (layouts identical) ----
    const int qr = 16 * wv + lr;
    const short8 aq = *(const short8*)(qkvb + pixt[(qr < WA) ? qr : 0] + lk);
    short8 bk[12];
    #pragma unroll
    for (int n = 0; n < 12; ++n) {
        const int kvr = n * 16 + lr;
        bk[n] = *(const short8*)(qkvb + pixt[(kvr < NKV) ? kvr : 0] + CDIM + lk);
        if (kvr >= NKV) bk[n] = (short8){0, 0, 0, 0, 0, 0, 0, 0};
    }

    // ---- V staging: issue all global loads first (MLP), then LDS writes ----
    u64 vdat[6];
    #pragma unroll
    for (int it = 0; it < 6; ++it) {
        const int idx = tid + it * 256;
        if (idx < NKV * 8)
            vdat[it] = *(const u64*)(qkvb + pixt[idx >> 3] + 2 * CDIM + (idx & 7) * 4);
    }
    #pragma unroll
    for (int it = 0; it < 6; ++it) {
        const int idx = tid + it * 256;
        if (idx < NKV * 8) {
            const int kv = idx >> 3, dq = idx & 7;             // d = dq*4 + j
            #pragma unroll
            for (int j = 0; j < 4; ++j)
                Vt[(dq * 4 + j) * VP + kv] = (u16)(vdat[it] >> (16 * j));
        }
    }
    for (int idx = tid; idx < 32 * (NKVT - NKV); idx += 256)
        Vt[(idx / (NKVT - NKV)) * VP + NKV + idx % (NKVT - NKV)] = 0;

    // ---- QK^T, SWAPPED: s[n] = K_n * Q^T  ->  lane: q=16wv+lr, kv=n*16+hi*4+r ----
    f32x4 s[12];
    #pragma unroll
    for (int n = 0; n < 12; ++n)
        s[n] = __builtin_amdgcn_mfma_f32_16x16x32_bf16(bk[n], aq, (f32x4){0.f, 0.f, 0.f, 0.f}, 0, 0, 0);

    // ---- scale + bias(+mask): coalesced float4 per lane ----
    const float scale = 0.17677669529663687f;  // 32^-0.5
    const float* btb = bt + (((size_t)head * 4 + wv) * 12) * 256 + lane * 4;
    #pragma unroll
    for (int n = 0; n < 12; ++n) {
        const float4 b4 = *(const float4*)(btb + n * 256);
        s[n][0] = fmaf(s[n][0], scale, b4.x);
        s[n][1] = fmaf(s[n][1], scale, b4.y);
        s[n][2] = fmaf(s[n][2], scale, b4.z);
        s[n][3] = fmaf(s[n][3], scale, b4.w);
    }

    // ---- softmax: lane-local over 48 values + 2-shfl cross-group reduce ----
    float m = -3.0e38f;
    #pragma unroll
    for (int n = 0; n < 12; ++n)
        #pragma unroll
        for (int r = 0; r < 4; ++r) m = fmaxf(m, s[n][r]);
    m = fmaxf(m, __shfl_xor(m, 16));
    m = fmaxf(m, __shfl_xor(m, 32));
    float t = 0.f;
    #pragma unroll
    for (int n = 0; n < 12; ++n)
        #pragma unroll
        for (int r = 0; r < 4; ++r) { const float e = __expf(s[n][r] - m); s[n][r] = e; t += e; }
    t += __shfl_xor(t, 16);
    t += __shfl_xor(t, 32);
    const float inv = 1.f / t;
    #pragma unroll
    for (int n = 0; n < 12; ++n)
        #pragma unroll
        for (int r = 0; r < 4; ++r) s[n][r] *= inv;

    __syncthreads();   // Vt staging complete before PV reads

    // ---- P -> LDS (packed b64: 4 consecutive kv per store), PV per half ----
    const int prow  = 16 * wv + lr;          // q row (wave-private range)
    const int pcol0 = (lane >> 4) * 4;       // hi*4
    f32x4 o[2] = {{0.f, 0.f, 0.f, 0.f}, {0.f, 0.f, 0.f, 0.f}};
    #pragma unroll
    for (int half = 0; half < 2; ++half) {
        #pragma unroll
        for (int j = 0; j < 6; ++j) {
            const int n = half * 6 + j;
            const u32 lo  = (u32)cvt_bf16_hw(s[n][0]) | ((u32)cvt_bf16_hw(s[n][1]) << 16);
            const u32 hi2 = (u32)cvt_bf16_hw(s[n][2]) | ((u32)cvt_bf16_hw(s[n][3]) << 16);
            *(u64*)(Ps + prow * PP + j * 16 + pcol0) = (u64)lo | ((u64)hi2 << 32);
        }
        #pragma unroll
        for (int kk = 0; kk < 3; ++kk) {
            const short8 pa = *(const short8*)(Ps + (16 * wv + lr) * PP + kk * 32 + lk);
            #pragma unroll
            for (int n0 = 0; n0 < 2; ++n0) {
                const short8 vb = *(const short8*)(Vt + (n0 * 16 + lr) * VP + (half * 3 + kk) * 32 + lk);
                o[n0] = __builtin_amdgcn_mfma_f32_16x16x32_bf16(pa, vb, o[n0], 0, 0, 0);
            }
        }
    }
    #pragma unroll
    for (int n0 = 0; n0 < 2; ++n0)
        #pragma unroll
        for (int r = 0; r < 4; ++r) {
            const int qi = qrow0 + r;
            if (qi < WA)
                aob[(size_t)(w * WA + qi) * CDIM + head * HD + n0 * 16 + lr] = cvt_bf16_hw(o[n0][r]);
        }
}

// ---------------- launch ----------------
extern "C" void kernel_launch(void* const* d_in, const int* in_sizes, int n_in,
                              void* d_out, int out_size, void* d_ws, size_t ws_size,
                              hipStream_t stream)
{
    const float* x      = (const float*)d_in[0];
    const float* qkv_w  = (const float*)d_in[1];
    const float* qkv_b  = (const float*)d_in[2];
    const float* proj_w = (const float*)d_in[3];
    const float* proj_b = (const float*)d_in[4];
    const float* rpbt   = (const float*)d_in[5];
    const float* rpbn   = (const float*)d_in[6];

    u16* xb   = (u16*)d_ws;                         // (25088, 512)
    u16* qkvb = xb + (size_t)NPIX * CDIM;           // (25088, 1536)
    u16* aob  = qkvb + (size_t)NPIX * QKVLD;        // (25088, 512)
    u16* qwb  = aob + (size_t)NPIX * CDIM;          // (1536, 512)
    u16* pwb  = qwb + (size_t)QKVLD * CDIM;         // (512, 512)
    float* bt = (float*)(pwb + (size_t)CDIM * CDIM);// 196608 floats
    const size_t need = ((size_t)NPIX * CDIM + (size_t)NPIX * QKVLD + (size_t)NPIX * CDIM
                         + (size_t)QKVLD * CDIM + (size_t)CDIM * CDIM) * sizeof(u16)
                        + (size_t)NHEADS * NKVT * 64 * sizeof(float);
    if (ws_size < need) return;

    {
        const int nx = NPIX * CDIM;
        cvt_bf16<<<(nx / 4 + 255) / 256, 256, 0, stream>>>(x, xb, nx);
        const int nq = QKVLD * CDIM;
        cvt_bf16<<<(nq / 4 + 255) / 256, 256, 0, stream>>>(qkv_w, qwb, nq);
        const int np = CDIM * CDIM;
        cvt_bf16<<<(np / 4 + 255) / 256, 256, 0, stream>>>(proj_w, pwb, np);
        build_bias<<<(NHEADS * NKVT * 64) / 256, 256, 0, stream>>>(rpbt, rpbn, bt);
    }

    // QKV projection (bf16 out)
    gemm_mfma<true><<<dim3(QKVLD / 128, NPIX / 128), 256, 0, stream>>>(
        xb, qwb, qkv_b, qkvb, NPIX, QKVLD, CDIM);

    // windowed attention (bf16 out)
    attn_win<<<NWIN * NHEADS, 256, 0, stream>>>(qkvb, bt, aob);

    // output projection (fp32 out)
    gemm_mfma<false><<<dim3(CDIM / 128, NPIX / 128), 256, 0, stream>>>(
        aob, pwb, proj_b, d_out, NPIX, CDIM, CDIM);
}

// Round 13
// 199.074 us; speedup vs baseline: 9.5682x; 1.0489x over previous
//
#include <hip/hip_runtime.h>
#include <hip/hip_bf16.h>
#include <math.h>

typedef unsigned short u16;
typedef unsigned int   u32;
typedef unsigned long long u64;
typedef __attribute__((ext_vector_type(8))) short short8;   // 8 bf16 (4 VGPR)
typedef __attribute__((ext_vector_type(4))) float f32x4;

// ---------------- problem constants ----------------
#define NHEADS 16
#define HD     32
#define WA     49
#define NROLL  132
#define NKV    181     // WA + NROLL
#define NKVT   192     // 12 tiles of 16
#define CDIM   512
#define QKVLD  1536
#define NPIX   25088   // 8*56*56
#define NWIN   512
// LDS pitches (bf16 elems)
#define VP 200        // Vt pitch
#define PP 104        // Ps pitch
#define LOG2E 1.4426950408889634f

__device__ __forceinline__ u16 f32_to_bf16(float f) {
    union { float f; u32 u; } x; x.f = f;
    u32 r = x.u + 0x7FFFu + ((x.u >> 16) & 1u);   // RNE
    return (u16)(r >> 16);
}
__device__ __forceinline__ u16 cvt_bf16_hw(float f) {
    __hip_bfloat16 h = __float2bfloat16(f);       // RNE
    return *reinterpret_cast<u16*>(&h);
}

// ---------------- fp32 -> bf16 conversion ----------------
__global__ __launch_bounds__(256) void cvt_bf16(const float* __restrict__ in,
                                                u16* __restrict__ out, int n) {
    int i = (blockIdx.x * 256 + threadIdx.x) * 4;
    if (i >= n) return;
    float4 v = *(const float4*)(in + i);
    *(ushort4*)(out + i) = make_ushort4(f32_to_bf16(v.x), f32_to_bf16(v.y),
                                        f32_to_bf16(v.z), f32_to_bf16(v.w));
}

// ---------------- bias table, swapped-QK^T C-fragment order, pre-scaled by log2e ----------------
// bt[head][qt(4)][n(12)][lane(64)][r(4)]:
//   qi = qt*16 + (lane&15) ; kv = n*16 + (lane>>4)*4 + r.  Mask baked (-1e30*log2e).
__global__ __launch_bounds__(256) void build_bias(
    const float* __restrict__ rpbt,   // (169,16)
    const float* __restrict__ rpbn,   // (16,49,132)
    float* __restrict__ bt)
{
    const int idx  = blockIdx.x * 256 + threadIdx.x;
    const int h    = idx / 12288;            // 4*12*64*4
    const int rem  = idx % 12288;
    const int qt   = rem / 3072;             // 12*64*4
    const int rem2 = rem % 3072;
    const int n    = rem2 / 256;             // 64*4
    const int rem3 = rem2 % 256;
    const int lane = rem3 / 4;
    const int r    = rem3 % 4;
    const int qi = qt * 16 + (lane & 15);
    const int kv = n * 16 + (lane >> 4) * 4 + r;
    float v = -1e30f;
    if (qi < WA && kv < NKV) {
        if (kv < WA) {
            const int r1 = qi / 7, c1 = qi % 7, r2 = kv / 7, c2 = kv % 7;
            v = rpbt[((r1 - r2 + 6) * 13 + (c1 - c2 + 6)) * NHEADS + h];
        } else {
            v = rpbn[(h * WA + qi) * NROLL + (kv - WA)];
        }
    }
    bt[idx] = v * LOG2E;                     // fold log2e: attn uses exp2 directly
}

// ---------------- bf16 MFMA GEMM: C = A @ W^T + bias ----------------
// 1D grid with XCD-chunked swizzle (gridDim.x divisible by 8).
template<bool STORE_BF16>
__global__ __launch_bounds__(256) void gemm_mfma(
    const u16* __restrict__ A, const u16* __restrict__ W,
    const float* __restrict__ bias, void* __restrict__ Cv,
    int M, int N, int K)
{
    __shared__ __align__(16) u16 As[128 * 32];
    __shared__ __align__(16) u16 Bs[128 * 32];
    const int tid = threadIdx.x;
    const int lane = tid & 63, wv = tid >> 6;
    const int bid = blockIdx.x;
    const int nid = (bid & 7) * (gridDim.x >> 3) + (bid >> 3);
    const int nbx = N >> 7;
    const int m0 = (nid / nbx) * 128, n0 = (nid % nbx) * 128;
    const int wr = (wv >> 1) * 64, wc = (wv & 1) * 64;
    const int lr = lane & 15;
    const int lk = (lane >> 4) * 8;
    const int srow = lane >> 2;
    const int scol = (lane & 3) * 8;

    f32x4 acc[4][4] = {};

    for (int k0 = 0; k0 < K; k0 += 32) {
        __syncthreads();
        #pragma unroll
        for (int blk = 0; blk < 2; ++blk) {
            const int r = wv * 32 + blk * 16;
            __builtin_amdgcn_global_load_lds(
                (const __attribute__((address_space(1))) void*)
                    (A + (size_t)(m0 + r + srow) * K + k0 + scol),
                (__attribute__((address_space(3))) void*)(As + r * 32), 16, 0, 0);
            __builtin_amdgcn_global_load_lds(
                (const __attribute__((address_space(1))) void*)
                    (W + (size_t)(n0 + r + srow) * K + k0 + scol),
                (__attribute__((address_space(3))) void*)(Bs + r * 32), 16, 0, 0);
        }
        __syncthreads();
        #pragma unroll
        for (int mi = 0; mi < 4; ++mi) {
            const short8 af = *(const short8*)(As + (wr + mi * 16 + lr) * 32 + lk);
            #pragma unroll
            for (int ni = 0; ni < 4; ++ni) {
                const short8 bf = *(const short8*)(Bs + (wc + ni * 16 + lr) * 32 + lk);
                acc[mi][ni] = __builtin_amdgcn_mfma_f32_16x16x32_bf16(af, bf, acc[mi][ni], 0, 0, 0);
            }
        }
    }

    const int hi = lane >> 4;
    if (STORE_BF16) {
        // LDS-transpose epilogue: coalesced u64 stores (16 lanes x 8B = 128B rows).
        // NOTE: u16 writes then u64 reads of the same LDS addresses within one
        // wave — TBAA says "no alias", so explicit compiler fences are REQUIRED
        // to stop the scheduler reordering ds ops (HW executes per-wave DS in
        // order once program order is fixed).
        __syncthreads();   // all waves done reading As/Bs
        u16* scr = ((wv < 2) ? As : Bs) + (wv & 1) * 2048;   // per-wave [16][68] u16
        u16* C = (u16*)Cv;
        #pragma unroll
        for (int mi = 0; mi < 4; ++mi) {
            #pragma unroll
            for (int ni = 0; ni < 4; ++ni) {
                const float bcol = bias[n0 + wc + ni * 16 + lr];
                #pragma unroll
                for (int r = 0; r < 4; ++r)
                    scr[(hi * 4 + r) * 68 + ni * 16 + lr] =
                        f32_to_bf16(acc[mi][ni][r] + bcol);
            }
            asm volatile("" ::: "memory");   // order: writes before reads
            #pragma unroll
            for (int i = 0; i < 4; ++i) {
                const int rl = i * 4 + hi;
                const u64 v = *(const u64*)(scr + rl * 68 + (lane & 15) * 4);
                *(u64*)(C + (size_t)(m0 + wr + mi * 16 + rl) * N
                          + n0 + wc + (lane & 15) * 4) = v;
            }
            asm volatile("" ::: "memory");   // order: reads before next overwrite
        }
    } else {
        const int col0 = n0 + wc + lr;
        #pragma unroll
        for (int ni = 0; ni < 4; ++ni) {
            const float bcol = bias[col0 + ni * 16];
            #pragma unroll
            for (int mi = 0; mi < 4; ++mi)
                #pragma unroll
                for (int r = 0; r < 4; ++r) {
                    const int row = m0 + wr + mi * 16 + hi * 4 + r;
                    ((float*)Cv)[(size_t)row * N + col0 + ni * 16] = acc[mi][ni][r] + bcol;
                }
        }
    }
}

// ---------------- rolled-neighbor offset table (np.nonzero order) ----------------
struct OffT { int dr[NROLL]; int dc[NROLL]; };
constexpr bool rvalid(int s, int r, int c) {
    return (s == 0) ? (r >= 4 || c >= 4) :
           (s == 1) ? (r >= 4 || c <= 2) :
           (s == 2) ? (r <= 2 || c >= 4) :
                      (r <= 2 || c <= 2);
}
constexpr OffT make_offt() {
    OffT t{};
    int p = 0;
    for (int s = 0; s < 4; ++s)
        for (int r = 0; r < 7; ++r)
            for (int c = 0; c < 7; ++c)
                if (rvalid(s, r, c)) {
                    const int sh = (s < 2) ? -3 : 3;
                    const int sw = (s & 1) ? 3 : -3;
                    t.dr[p] = r - sh;   // rolled[h] = orig[h - sh]
                    t.dc[p] = c - sw;
                    ++p;
                }
    return t;
}
__device__ constexpr OffT OFT = make_offt();

// ---------------- MFMA window attention (swapped QK^T, no-max softmax) ----------------
__global__ __launch_bounds__(256, 6) void attn_win(
    const u16* __restrict__ qkvb,    // (25088, 1536) bf16: q|k|v
    const float* __restrict__ bt,    // swapped-fragment bias table (x log2e)
    u16* __restrict__ aob)           // (25088, 512) bf16
{
    // Vt 12800 + Ps 13312 + pixt 724 = 26,836 B  -> 6 blocks/CU
    __shared__ __align__(16) u16 Vt[32 * VP];   // V transposed: [d][kv]
    __shared__ __align__(16) u16 Ps[64 * PP];   // P bf16 (two 96-col halves)
    __shared__ int pixt[NKV];

    const int tid  = threadIdx.x;
    const int lane = tid & 63, wv = tid >> 6;
    // XCD swizzle: contiguous (window, head) chunk per XCD -> K/V L2 reuse
    const int bid  = blockIdx.x;
    const int nid  = (bid & 7) * (NWIN * NHEADS / 8) + (bid >> 3);
    const int w    = nid >> 4;
    const int head = nid & 15;
    const int b    = w >> 6;
    const int h0   = ((w >> 3) & 7) * 7;
    const int w0c  = (w & 7) * 7;
    const int pixbase = b * 3136;

    // ---- pixel-row offset table ----
    if (tid < NKV) {
        int h, wc;
        if (tid < WA) { h = h0 + tid / 7; wc = w0c + tid % 7; }
        else {
            const int i = tid - WA;
            h = h0 + OFT.dr[i];  h += (h < 0) ? 56 : 0;  h -= (h >= 56) ? 56 : 0;
            wc = w0c + OFT.dc[i]; wc += (wc < 0) ? 56 : 0; wc -= (wc >= 56) ? 56 : 0;
        }
        pixt[tid] = (pixbase + h * 56 + wc) * QKVLD + head * HD;
    }
    __syncthreads();

    const int lr = lane & 15;
    const int lk = (lane >> 4) * 8;
    const int qrow0 = 16 * wv + (lane >> 4) * 4;   // + r (PV output rows)

    // ---- Q fragment + 12 K fragments direct from global ----
    const int qr = 16 * wv + lr;
    const short8 aq = *(const short8*)(qkvb + pixt[(qr < WA) ? qr : 0] + lk);
    short8 bk[12];
    #pragma unroll
    for (int n = 0; n < 12; ++n) {
        const int kvr = n * 16 + lr;
        // pad cols read row 0 (finite); -1e30 bias masks them after QK^T
        bk[n] = *(const short8*)(qkvb + pixt[(kvr < NKV) ? kvr : 0] + CDIM + lk);
    }

    // ---- V staging: issue all global loads first, then LDS writes ----
    u64 vdat[6];
    #pragma unroll
    for (int it = 0; it < 6; ++it) {
        const int idx = tid + it * 256;
        if (idx < NKV * 8)
            vdat[it] = *(const u64*)(qkvb + pixt[idx >> 3] + 2 * CDIM + (idx & 7) * 4);
    }
    #pragma unroll
    for (int it = 0; it < 6; ++it) {
        const int idx = tid + it * 256;
        if (idx < NKV * 8) {
            const int kv = idx >> 3, dq = idx & 7;             // d = dq*4 + j
            #pragma unroll
            for (int j = 0; j < 4; ++j)
                Vt[(dq * 4 + j) * VP + kv] = (u16)(vdat[it] >> (16 * j));
        }
    }
    for (int idx = tid; idx < 32 * (NKVT - NKV); idx += 256)
        Vt[(idx / (NKVT - NKV)) * VP + NKV + idx % (NKVT - NKV)] = 0;

    // ---- QK^T, SWAPPED: lane owns q=16wv+lr; kv = n*16 + hi*4 + r ----
    f32x4 s[12];
    #pragma unroll
    for (int n = 0; n < 12; ++n)
        s[n] = __builtin_amdgcn_mfma_f32_16x16x32_bf16(bk[n], aq, (f32x4){0.f, 0.f, 0.f, 0.f}, 0, 0, 0);

    // ---- scale*log2e + bias*log2e (mask baked); then exp2 directly ----
    const float scale2 = 0.17677669529663687f * LOG2E;
    const float* btb = bt + (((size_t)head * 4 + wv) * 12) * 256 + lane * 4;
    #pragma unroll
    for (int n = 0; n < 12; ++n) {
        const float4 b4 = *(const float4*)(btb + n * 256);
        s[n][0] = fmaf(s[n][0], scale2, b4.x);
        s[n][1] = fmaf(s[n][1], scale2, b4.y);
        s[n][2] = fmaf(s[n][2], scale2, b4.z);
        s[n][3] = fmaf(s[n][3], scale2, b4.w);
    }

    // ---- softmax, no max-subtraction (logits data-bounded; mask->exp2->0) ----
    float t = 0.f;
    #pragma unroll
    for (int n = 0; n < 12; ++n)
        #pragma unroll
        for (int r = 0; r < 4; ++r) { const float e = exp2f(s[n][r]); s[n][r] = e; t += e; }
    t += __shfl_xor(t, 16);
    t += __shfl_xor(t, 32);
    const float inv = 1.f / fmaxf(t, 1e-30f);   // pad q-rows: t==0 -> P=0, no NaN
    #pragma unroll
    for (int n = 0; n < 12; ++n)
        #pragma unroll
        for (int r = 0; r < 4; ++r) s[n][r] *= inv;

    __syncthreads();   // Vt staging complete before PV reads

    // ---- P -> LDS (packed b64), PV per 96-col half; fences order u64 writes
    //      vs short8 reads of the same wave-private LDS rows (TBAA hazard) ----
    const int prow  = 16 * wv + lr;
    const int pcol0 = (lane >> 4) * 4;
    f32x4 o[2] = {{0.f, 0.f, 0.f, 0.f}, {0.f, 0.f, 0.f, 0.f}};
    #pragma unroll
    for (int half = 0; half < 2; ++half) {
        #pragma unroll
        for (int j = 0; j < 6; ++j) {
            const int n = half * 6 + j;
            const u32 lo  = (u32)cvt_bf16_hw(s[n][0]) | ((u32)cvt_bf16_hw(s[n][1]) << 16);
            const u32 hi2 = (u32)cvt_bf16_hw(s[n][2]) | ((u32)cvt_bf16_hw(s[n][3]) << 16);
            *(u64*)(Ps + prow * PP + j * 16 + pcol0) = (u64)lo | ((u64)hi2 << 32);
        }
        asm volatile("" ::: "memory");   // writes before reads
        #pragma unroll
        for (int kk = 0; kk < 3; ++kk) {
            const short8 pa = *(const short8*)(Ps + (16 * wv + lr) * PP + kk * 32 + lk);
            #pragma unroll
            for (int n0 = 0; n0 < 2; ++n0) {
                const short8 vb = *(const short8*)(Vt + (n0 * 16 + lr) * VP + (half * 3 + kk) * 32 + lk);
                o[n0] = __builtin_amdgcn_mfma_f32_16x16x32_bf16(pa, vb, o[n0], 0, 0, 0);
            }
        }
        asm volatile("" ::: "memory");   // reads before next half's overwrite
    }
    #pragma unroll
    for (int n0 = 0; n0 < 2; ++n0)
        #pragma unroll
        for (int r = 0; r < 4; ++r) {
            const int qi = qrow0 + r;
            if (qi < WA)
                aob[(size_t)(w * WA + qi) * CDIM + head * HD + n0 * 16 + lr] = cvt_bf16_hw(o[n0][r]);
        }
}

// ---------------- launch ----------------
extern "C" void kernel_launch(void* const* d_in, const int* in_sizes, int n_in,
                              void* d_out, int out_size, void* d_ws, size_t ws_size,
                              hipStream_t stream)
{
    const float* x      = (const float*)d_in[0];
    const float* qkv_w  = (const float*)d_in[1];
    const float* qkv_b  = (const float*)d_in[2];
    const float* proj_w = (const float*)d_in[3];
    const float* proj_b = (const float*)d_in[4];
    const float* rpbt   = (const float*)d_in[5];
    const float* rpbn   = (const float*)d_in[6];

    u16* xb   = (u16*)d_ws;                         // (25088, 512)
    u16* qkvb = xb + (size_t)NPIX * CDIM;           // (25088, 1536)
    u16* aob  = qkvb + (size_t)NPIX * QKVLD;        // (25088, 512)
    u16* qwb  = aob + (size_t)NPIX * CDIM;          // (1536, 512)
    u16* pwb  = qwb + (size_t)QKVLD * CDIM;         // (512, 512)
    float* bt = (float*)(pwb + (size_t)CDIM * CDIM);// 196608 floats
    const size_t need = ((size_t)NPIX * CDIM + (size_t)NPIX * QKVLD + (size_t)NPIX * CDIM
                         + (size_t)QKVLD * CDIM + (size_t)CDIM * CDIM) * sizeof(u16)
                        + (size_t)NHEADS * NKVT * 64 * sizeof(float);
    if (ws_size < need) return;

    {
        const int nx = NPIX * CDIM;
        cvt_bf16<<<(nx / 4 + 255) / 256, 256, 0, stream>>>(x, xb, nx);
        const int nq = QKVLD * CDIM;
        cvt_bf16<<<(nq / 4 + 255) / 256, 256, 0, stream>>>(qkv_w, qwb, nq);
        const int np = CDIM * CDIM;
        cvt_bf16<<<(np / 4 + 255) / 256, 256, 0, stream>>>(proj_w, pwb, np);
        build_bias<<<(NHEADS * NKVT * 64) / 256, 256, 0, stream>>>(rpbt, rpbn, bt);
    }

    // QKV projection (bf16 out), 1D grid 2352 = 8*294
    gemm_mfma<true><<<(NPIX / 128) * (QKVLD / 128), 256, 0, stream>>>(
        xb, qwb, qkv_b, qkvb, NPIX, QKVLD, CDIM);

    // windowed attention (bf16 out)
    attn_win<<<NWIN * NHEADS, 256, 0, stream>>>(qkvb, bt, aob);

    // output projection (fp32 out), 1D grid 784 = 8*98
    gemm_mfma<false><<<(NPIX / 128) * (CDIM / 128), 256, 0, stream>>>(
        aob, pwb, proj_b, d_out, NPIX, CDIM, CDIM);
}

// Round 14
// 192.350 us; speedup vs baseline: 9.9027x; 1.0350x over previous
//
#include <hip/hip_runtime.h>
#include <hip/hip_bf16.h>
#include <math.h>

typedef unsigned short u16;
typedef unsigned int   u32;
typedef unsigned long long u64;
typedef __attribute__((ext_vector_type(8))) short short8;   // 8 bf16 (4 VGPR)
typedef __attribute__((ext_vector_type(4))) float f32x4;

// ---------------- problem constants ----------------
#define NHEADS 16
#define HD     32
#define WA     49
#define NROLL  132
#define NKV    181     // WA + NROLL
#define NKVT   192     // 12 tiles of 16
#define CDIM   512
#define QKVLD  1536
#define NPIX   25088   // 8*56*56
#define NWIN   512
// LDS pitches (bf16 elems)
#define VP 200        // Vt pitch
#define PP 104        // Ps pitch
#define LOG2E 1.4426950408889634f

__device__ __forceinline__ u16 f32_to_bf16(float f) {
    union { float f; u32 u; } x; x.f = f;
    u32 r = x.u + 0x7FFFu + ((x.u >> 16) & 1u);   // RNE
    return (u16)(r >> 16);
}
__device__ __forceinline__ u16 cvt_bf16_hw(float f) {
    __hip_bfloat16 h = __float2bfloat16(f);       // RNE
    return *reinterpret_cast<u16*>(&h);
}

// ---------------- fused fp32 -> bf16 conversion (3 buffers, 1 launch) ----------------
__global__ __launch_bounds__(256) void cvt3_bf16(
    const float* __restrict__ in0, u16* __restrict__ out0, int n0,
    const float* __restrict__ in1, u16* __restrict__ out1, int n1,
    const float* __restrict__ in2, u16* __restrict__ out2, int n2)
{
    int i = (blockIdx.x * 256 + threadIdx.x) * 4;
    const float* in; u16* out;
    if (i < n0)            { in = in0; out = out0; }
    else if (i < n0 + n1)  { in = in1; out = out1; i -= n0; }
    else if (i < n0 + n1 + n2) { in = in2; out = out2; i -= n0 + n1; }
    else return;
    float4 v = *(const float4*)(in + i);
    *(ushort4*)(out + i) = make_ushort4(f32_to_bf16(v.x), f32_to_bf16(v.y),
                                        f32_to_bf16(v.z), f32_to_bf16(v.w));
}

// ---------------- bias table, swapped-QK^T C-fragment order, pre-scaled by log2e ----------------
// bt[head][qt(4)][n(12)][lane(64)][r(4)]:
//   qi = qt*16 + (lane&15) ; kv = n*16 + (lane>>4)*4 + r.  Mask baked (-1e30*log2e).
__global__ __launch_bounds__(256) void build_bias(
    const float* __restrict__ rpbt,   // (169,16)
    const float* __restrict__ rpbn,   // (16,49,132)
    float* __restrict__ bt)
{
    const int idx  = blockIdx.x * 256 + threadIdx.x;
    const int h    = idx / 12288;            // 4*12*64*4
    const int rem  = idx % 12288;
    const int qt   = rem / 3072;             // 12*64*4
    const int rem2 = rem % 3072;
    const int n    = rem2 / 256;             // 64*4
    const int rem3 = rem2 % 256;
    const int lane = rem3 / 4;
    const int r    = rem3 % 4;
    const int qi = qt * 16 + (lane & 15);
    const int kv = n * 16 + (lane >> 4) * 4 + r;
    float v = -1e30f;
    if (qi < WA && kv < NKV) {
        if (kv < WA) {
            const int r1 = qi / 7, c1 = qi % 7, r2 = kv / 7, c2 = kv % 7;
            v = rpbt[((r1 - r2 + 6) * 13 + (c1 - c2 + 6)) * NHEADS + h];
        } else {
            v = rpbn[(h * WA + qi) * NROLL + (kv - WA)];
        }
    }
    bt[idx] = v * LOG2E;                     // fold log2e: attn uses exp2 directly
}

// ---------------- bf16 MFMA GEMM: C = A @ W^T + bias ----------------
// 1D grid with XCD-chunked swizzle (gridDim.x divisible by 8).
template<bool STORE_BF16>
__global__ __launch_bounds__(256) void gemm_mfma(
    const u16* __restrict__ A, const u16* __restrict__ W,
    const float* __restrict__ bias, void* __restrict__ Cv,
    int M, int N, int K)
{
    __shared__ __align__(16) u16 As[128 * 32];
    __shared__ __align__(16) u16 Bs[128 * 32];
    const int tid = threadIdx.x;
    const int lane = tid & 63, wv = tid >> 6;
    const int bid = blockIdx.x;
    const int nid = (bid & 7) * (gridDim.x >> 3) + (bid >> 3);
    const int nbx = N >> 7;
    const int m0 = (nid / nbx) * 128, n0 = (nid % nbx) * 128;
    const int wr = (wv >> 1) * 64, wc = (wv & 1) * 64;
    const int lr = lane & 15;
    const int lk = (lane >> 4) * 8;
    const int srow = lane >> 2;
    const int scol = (lane & 3) * 8;

    f32x4 acc[4][4] = {};

    for (int k0 = 0; k0 < K; k0 += 32) {
        __syncthreads();
        #pragma unroll
        for (int blk = 0; blk < 2; ++blk) {
            const int r = wv * 32 + blk * 16;
            __builtin_amdgcn_global_load_lds(
                (const __attribute__((address_space(1))) void*)
                    (A + (size_t)(m0 + r + srow) * K + k0 + scol),
                (__attribute__((address_space(3))) void*)(As + r * 32), 16, 0, 0);
            __builtin_amdgcn_global_load_lds(
                (const __attribute__((address_space(1))) void*)
                    (W + (size_t)(n0 + r + srow) * K + k0 + scol),
                (__attribute__((address_space(3))) void*)(Bs + r * 32), 16, 0, 0);
        }
        __syncthreads();
        #pragma unroll
        for (int mi = 0; mi < 4; ++mi) {
            const short8 af = *(const short8*)(As + (wr + mi * 16 + lr) * 32 + lk);
            #pragma unroll
            for (int ni = 0; ni < 4; ++ni) {
                const short8 bf = *(const short8*)(Bs + (wc + ni * 16 + lr) * 32 + lk);
                acc[mi][ni] = __builtin_amdgcn_mfma_f32_16x16x32_bf16(af, bf, acc[mi][ni], 0, 0, 0);
            }
        }
    }

    const int hi = lane >> 4;
    if (STORE_BF16) {
        // LDS-transpose epilogue: coalesced u64 stores. Fences required: u16
        // writes then u64 reads of same LDS addrs (TBAA would allow reorder).
        __syncthreads();   // all waves done reading As/Bs
        u16* scr = ((wv < 2) ? As : Bs) + (wv & 1) * 2048;   // per-wave [16][68] u16
        u16* C = (u16*)Cv;
        #pragma unroll
        for (int mi = 0; mi < 4; ++mi) {
            #pragma unroll
            for (int ni = 0; ni < 4; ++ni) {
                const float bcol = bias[n0 + wc + ni * 16 + lr];
                #pragma unroll
                for (int r = 0; r < 4; ++r)
                    scr[(hi * 4 + r) * 68 + ni * 16 + lr] =
                        f32_to_bf16(acc[mi][ni][r] + bcol);
            }
            asm volatile("" ::: "memory");   // order: writes before reads
            #pragma unroll
            for (int i = 0; i < 4; ++i) {
                const int rl = i * 4 + hi;
                const u64 v = *(const u64*)(scr + rl * 68 + (lane & 15) * 4);
                *(u64*)(C + (size_t)(m0 + wr + mi * 16 + rl) * N
                          + n0 + wc + (lane & 15) * 4) = v;
            }
            asm volatile("" ::: "memory");   // order: reads before next overwrite
        }
    } else {
        const int col0 = n0 + wc + lr;
        #pragma unroll
        for (int ni = 0; ni < 4; ++ni) {
            const float bcol = bias[col0 + ni * 16];
            #pragma unroll
            for (int mi = 0; mi < 4; ++mi)
                #pragma unroll
                for (int r = 0; r < 4; ++r) {
                    const int row = m0 + wr + mi * 16 + hi * 4 + r;
                    ((float*)Cv)[(size_t)row * N + col0 + ni * 16] = acc[mi][ni][r] + bcol;
                }
        }
    }
}

// ---------------- rolled-neighbor offset table (np.nonzero order) ----------------
struct OffT { int dr[NROLL]; int dc[NROLL]; };
constexpr bool rvalid(int s, int r, int c) {
    return (s == 0) ? (r >= 4 || c >= 4) :
           (s == 1) ? (r >= 4 || c <= 2) :
           (s == 2) ? (r <= 2 || c >= 4) :
                      (r <= 2 || c <= 2);
}
constexpr OffT make_offt() {
    OffT t{};
    int p = 0;
    for (int s = 0; s < 4; ++s)
        for (int r = 0; r < 7; ++r)
            for (int c = 0; c < 7; ++c)
                if (rvalid(s, r, c)) {
                    const int sh = (s < 2) ? -3 : 3;
                    const int sw = (s & 1) ? 3 : -3;
                    t.dr[p] = r - sh;   // rolled[h] = orig[h - sh]
                    t.dc[p] = c - sw;
                    ++p;
                }
    return t;
}
__device__ constexpr OffT OFT = make_offt();

// ---------------- MFMA window attention (swapped QK^T, no-max softmax) ----------------
// __launch_bounds__(256,4): 128-VGPR budget. Live state (~115 regs: s[12]=48,
// bk[12]=48, addr) MUST fit — (256,6)'s 85-reg cap forced ~40MB/dispatch of
// scratch spill (r10-r13 WRITE_SIZE 66-82MB vs 25MB ideal) and 3x VALU inflation.
__global__ __launch_bounds__(256, 4) void attn_win(
    const u16* __restrict__ qkvb,    // (25088, 1536) bf16: q|k|v
    const float* __restrict__ bt,    // swapped-fragment bias table (x log2e)
    u16* __restrict__ aob)           // (25088, 512) bf16
{
    // Vt 12800 + Ps 13312 + pixt 724 = 26,836 B
    __shared__ __align__(16) u16 Vt[32 * VP];   // V transposed: [d][kv]
    __shared__ __align__(16) u16 Ps[64 * PP];   // P bf16 (two 96-col halves)
    __shared__ int pixt[NKV];

    const int tid  = threadIdx.x;
    const int lane = tid & 63, wv = tid >> 6;
    // XCD swizzle: contiguous (window, head) chunk per XCD -> K/V L2 reuse
    const int bid  = blockIdx.x;
    const int nid  = (bid & 7) * (NWIN * NHEADS / 8) + (bid >> 3);
    const int w    = nid >> 4;
    const int head = nid & 15;
    const int b    = w >> 6;
    const int h0   = ((w >> 3) & 7) * 7;
    const int w0c  = (w & 7) * 7;
    const int pixbase = b * 3136;

    // ---- pixel-row offset table ----
    if (tid < NKV) {
        int h, wc;
        if (tid < WA) { h = h0 + tid / 7; wc = w0c + tid % 7; }
        else {
            const int i = tid - WA;
            h = h0 + OFT.dr[i];  h += (h < 0) ? 56 : 0;  h -= (h >= 56) ? 56 : 0;
            wc = w0c + OFT.dc[i]; wc += (wc < 0) ? 56 : 0; wc -= (wc >= 56) ? 56 : 0;
        }
        pixt[tid] = (pixbase + h * 56 + wc) * QKVLD + head * HD;
    }
    __syncthreads();

    const int lr = lane & 15;
    const int lk = (lane >> 4) * 8;
    const int qrow0 = 16 * wv + (lane >> 4) * 4;   // + r (PV output rows)

    // ---- Q fragment + 12 K fragments direct from global ----
    const int qr = 16 * wv + lr;
    const short8 aq = *(const short8*)(qkvb + pixt[(qr < WA) ? qr : 0] + lk);
    short8 bk[12];
    #pragma unroll
    for (int n = 0; n < 12; ++n) {
        const int kvr = n * 16 + lr;
        // pad cols read row 0 (finite); -1e30 bias masks them after QK^T
        bk[n] = *(const short8*)(qkvb + pixt[(kvr < NKV) ? kvr : 0] + CDIM + lk);
    }

    // ---- V staging: issue all global loads first, then LDS writes ----
    u64 vdat[6];
    #pragma unroll
    for (int it = 0; it < 6; ++it) {
        const int idx = tid + it * 256;
        if (idx < NKV * 8)
            vdat[it] = *(const u64*)(qkvb + pixt[idx >> 3] + 2 * CDIM + (idx & 7) * 4);
    }
    #pragma unroll
    for (int it = 0; it < 6; ++it) {
        const int idx = tid + it * 256;
        if (idx < NKV * 8) {
            const int kv = idx >> 3, dq = idx & 7;             // d = dq*4 + j
            #pragma unroll
            for (int j = 0; j < 4; ++j)
                Vt[(dq * 4 + j) * VP + kv] = (u16)(vdat[it] >> (16 * j));
        }
    }
    for (int idx = tid; idx < 32 * (NKVT - NKV); idx += 256)
        Vt[(idx / (NKVT - NKV)) * VP + NKV + idx % (NKVT - NKV)] = 0;

    // ---- QK^T, SWAPPED: lane owns q=16wv+lr; kv = n*16 + hi*4 + r ----
    f32x4 s[12];
    __builtin_amdgcn_s_setprio(1);
    #pragma unroll
    for (int n = 0; n < 12; ++n)
        s[n] = __builtin_amdgcn_mfma_f32_16x16x32_bf16(bk[n], aq, (f32x4){0.f, 0.f, 0.f, 0.f}, 0, 0, 0);
    __builtin_amdgcn_s_setprio(0);

    // ---- scale*log2e + bias*log2e (mask baked); then exp2 directly ----
    const float scale2 = 0.17677669529663687f * LOG2E;
    const float* btb = bt + (((size_t)head * 4 + wv) * 12) * 256 + lane * 4;
    #pragma unroll
    for (int n = 0; n < 12; ++n) {
        const float4 b4 = *(const float4*)(btb + n * 256);
        s[n][0] = fmaf(s[n][0], scale2, b4.x);
        s[n][1] = fmaf(s[n][1], scale2, b4.y);
        s[n][2] = fmaf(s[n][2], scale2, b4.z);
        s[n][3] = fmaf(s[n][3], scale2, b4.w);
    }

    // ---- softmax, no max-subtraction (logits data-bounded; mask->exp2->0) ----
    float t = 0.f;
    #pragma unroll
    for (int n = 0; n < 12; ++n)
        #pragma unroll
        for (int r = 0; r < 4; ++r) { const float e = exp2f(s[n][r]); s[n][r] = e; t += e; }
    t += __shfl_xor(t, 16);
    t += __shfl_xor(t, 32);
    const float inv = 1.f / fmaxf(t, 1e-30f);   // pad q-rows: t==0 -> P=0, no NaN
    #pragma unroll
    for (int n = 0; n < 12; ++n)
        #pragma unroll
        for (int r = 0; r < 4; ++r) s[n][r] *= inv;

    __syncthreads();   // Vt staging complete before PV reads

    // ---- P -> LDS (packed b64), PV per 96-col half; fences order u64 writes
    //      vs short8 reads of the same wave-private LDS rows (TBAA hazard) ----
    const int prow  = 16 * wv + lr;
    const int pcol0 = (lane >> 4) * 4;
    f32x4 o[2] = {{0.f, 0.f, 0.f, 0.f}, {0.f, 0.f, 0.f, 0.f}};
    #pragma unroll
    for (int half = 0; half < 2; ++half) {
        #pragma unroll
        for (int j = 0; j < 6; ++j) {
            const int n = half * 6 + j;
            const u32 lo  = (u32)cvt_bf16_hw(s[n][0]) | ((u32)cvt_bf16_hw(s[n][1]) << 16);
            const u32 hi2 = (u32)cvt_bf16_hw(s[n][2]) | ((u32)cvt_bf16_hw(s[n][3]) << 16);
            *(u64*)(Ps + prow * PP + j * 16 + pcol0) = (u64)lo | ((u64)hi2 << 32);
        }
        asm volatile("" ::: "memory");   // writes before reads
        __builtin_amdgcn_s_setprio(1);
        #pragma unroll
        for (int kk = 0; kk < 3; ++kk) {
            const short8 pa = *(const short8*)(Ps + (16 * wv + lr) * PP + kk * 32 + lk);
            #pragma unroll
            for (int n0 = 0; n0 < 2; ++n0) {
                const short8 vb = *(const short8*)(Vt + (n0 * 16 + lr) * VP + (half * 3 + kk) * 32 + lk);
                o[n0] = __builtin_amdgcn_mfma_f32_16x16x32_bf16(pa, vb, o[n0], 0, 0, 0);
            }
        }
        __builtin_amdgcn_s_setprio(0);
        asm volatile("" ::: "memory");   // reads before next half's overwrite
    }
    #pragma unroll
    for (int n0 = 0; n0 < 2; ++n0)
        #pragma unroll
        for (int r = 0; r < 4; ++r) {
            const int qi = qrow0 + r;
            if (qi < WA)
                aob[(size_t)(w * WA + qi) * CDIM + head * HD + n0 * 16 + lr] = cvt_bf16_hw(o[n0][r]);
        }
}

// ---------------- launch ----------------
extern "C" void kernel_launch(void* const* d_in, const int* in_sizes, int n_in,
                              void* d_out, int out_size, void* d_ws, size_t ws_size,
                              hipStream_t stream)
{
    const float* x      = (const float*)d_in[0];
    const float* qkv_w  = (const float*)d_in[1];
    const float* qkv_b  = (const float*)d_in[2];
    const float* proj_w = (const float*)d_in[3];
    const float* proj_b = (const float*)d_in[4];
    const float* rpbt   = (const float*)d_in[5];
    const float* rpbn   = (const float*)d_in[6];

    u16* xb   = (u16*)d_ws;                         // (25088, 512)
    u16* qkvb = xb + (size_t)NPIX * CDIM;           // (25088, 1536)
    u16* aob  = qkvb + (size_t)NPIX * QKVLD;        // (25088, 512)
    u16* qwb  = aob + (size_t)NPIX * CDIM;          // (1536, 512)
    u16* pwb  = qwb + (size_t)QKVLD * CDIM;         // (512, 512)
    float* bt = (float*)(pwb + (size_t)CDIM * CDIM);// 196608 floats
    const size_t need = ((size_t)NPIX * CDIM + (size_t)NPIX * QKVLD + (size_t)NPIX * CDIM
                         + (size_t)QKVLD * CDIM + (size_t)CDIM * CDIM) * sizeof(u16)
                        + (size_t)NHEADS * NKVT * 64 * sizeof(float);
    if (ws_size < need) return;

    {
        const int nx = NPIX * CDIM;           // 12,845,056
        const int nq = QKVLD * CDIM;          //    786,432
        const int np = CDIM * CDIM;           //    262,144
        const int tot4 = (nx + nq + np) / 4;
        cvt3_bf16<<<(tot4 + 255) / 256, 256, 0, stream>>>(
            x, xb, nx, qkv_w, qwb, nq, proj_w, pwb, np);
        build_bias<<<(NHEADS * NKVT * 64) / 256, 256, 0, stream>>>(rpbt, rpbn, bt);
    }

    // QKV projection (bf16 out), 1D grid 2352 = 8*294
    gemm_mfma<true><<<(NPIX / 128) * (QKVLD / 128), 256, 0, stream>>>(
        xb, qwb, qkv_b, qkvb, NPIX, QKVLD, CDIM);

    // windowed attention (bf16 out)
    attn_win<<<NWIN * NHEADS, 256, 0, stream>>>(qkvb, bt, aob);

    // output projection (fp32 out), 1D grid 784 = 8*98
    gemm_mfma<false><<<(NPIX / 128) * (CDIM / 128), 256, 0, stream>>>(
        aob, pwb, proj_b, d_out, NPIX, CDIM, CDIM);
}